// Round 1
// 1200.407 us; speedup vs baseline: 1.0581x; 1.0581x over previous
//
#include <hip/hip_runtime.h>

#define B_ 16
#define N_ 4096
#define S_ 1024
#define K_ 32
#define NSLOT 128
#define CNT_F 524288.0f   // B*S*K
#define RWS 524288        // total rows = B*S*K

typedef unsigned short ushort_t;
typedef short short8 __attribute__((ext_vector_type(8)));
typedef float floatx4 __attribute__((ext_vector_type(4)));
union U4S8 { uint4 u; short8 v; };

__device__ __forceinline__ ushort_t f2bf(float f) {  // RNE
  unsigned u = __float_as_uint(f);
  unsigned r = (u + 0x7fffu + ((u >> 16) & 1u)) >> 16;
  return (ushort_t)r;
}
__device__ __forceinline__ unsigned pkrne(float a, float b) {
  return (unsigned)f2bf(a) | ((unsigned)f2bf(b) << 16);
}
__device__ __forceinline__ unsigned pkhu(float a, float b) {  // half-up pair
  return ((__float_as_uint(a) + 0x8000u) >> 16) |
         ((__float_as_uint(b) + 0x8000u) & 0xffff0000u);
}

// unpack 8 bf16, apply bn scale/shift + relu, repack as bf16 (half-up)
__device__ __forceinline__ uint4 bn_relu_pack(uint4 xv, float4 sca, float4 scb,
                                              float4 sha, float4 shb) {
  float x0 = __uint_as_float(xv.x << 16);
  float x1 = __uint_as_float(xv.x & 0xffff0000u);
  float x2 = __uint_as_float(xv.y << 16);
  float x3 = __uint_as_float(xv.y & 0xffff0000u);
  float x4 = __uint_as_float(xv.z << 16);
  float x5 = __uint_as_float(xv.z & 0xffff0000u);
  float x6 = __uint_as_float(xv.w << 16);
  float x7 = __uint_as_float(xv.w & 0xffff0000u);
  x0 = fmaxf(fmaf(x0, sca.x, sha.x), 0.0f);
  x1 = fmaxf(fmaf(x1, sca.y, sha.y), 0.0f);
  x2 = fmaxf(fmaf(x2, sca.z, sha.z), 0.0f);
  x3 = fmaxf(fmaf(x3, sca.w, sha.w), 0.0f);
  x4 = fmaxf(fmaf(x4, scb.x, shb.x), 0.0f);
  x5 = fmaxf(fmaf(x5, scb.y, shb.y), 0.0f);
  x6 = fmaxf(fmaf(x6, scb.z, shb.z), 0.0f);
  x7 = fmaxf(fmaf(x7, scb.w, shb.w), 0.0f);
  return make_uint4(pkhu(x0, x1), pkhu(x2, x3), pkhu(x4, x5), pkhu(x6, x7));
}

// ---------------------------------------------------------------- FPS params
#define FPS_T 256
#define FPS_P (N_ / FPS_T)
#define FPS_W (FPS_T / 64)

template <int CTRL>
__device__ __forceinline__ void dpp_max_u64(unsigned& hi, unsigned& lo) {
  unsigned h2 = (unsigned)__builtin_amdgcn_update_dpp(0, (int)hi, CTRL, 0xf, 0xf, true);
  unsigned l2 = (unsigned)__builtin_amdgcn_update_dpp(0, (int)lo, CTRL, 0xf, 0xf, true);
  bool take = (h2 > hi) || (h2 == hi && l2 > lo);
  hi = take ? h2 : hi;
  lo = take ? l2 : lo;
}

// ---------------------------------------------------------------- prep (ptnorm + weights)
__global__ __launch_bounds__(256) void prep_all(
    const float* __restrict__ xyz, float* __restrict__ pt,
    const float* __restrict__ w0, const float* __restrict__ w1,
    const float* __restrict__ w2, ushort_t* __restrict__ wB0,
    ushort_t* __restrict__ wB1, ushort_t* __restrict__ wB2) {
  int i = blockIdx.x * 256 + threadIdx.x;  // < 65536 = B*N
  float x = xyz[(size_t)i * 3 + 0];
  float y = xyz[(size_t)i * 3 + 1];
  float z = xyz[(size_t)i * 3 + 2];
  pt[i] = __fadd_rn(__fadd_rn(__fmul_rn(x, x), __fmul_rn(y, y)), __fmul_rn(z, z));
  // wB0: [o][96] = [p-weights(64), xyz-weights(3), zeros(29)]
  if (i < 64 * 96) {
    int o = i / 96, c = i % 96;
    ushort_t v = 0;
    if (c < 64) v = f2bf(w0[o * 67 + 3 + c]);
    else if (c < 67) v = f2bf(w0[o * 67 + (c - 64)]);
    wB0[i] = v;
  }
  if (i < 64 * 64) wB1[i] = f2bf(w1[i]);
  if (i < 128 * 64) wB2[i] = f2bf(w2[i]);
}

// ================================================================ fused
// Blocks 0..15: FPS producer (one per batch), publishing each sample's index
// via device-scope relaxed atomic (value doubles as ready flag).
// Blocks 16..255: consumer blocks; each of their 4 waves independently
// processes samples in readiness order r = s*16 + b: spin for index, kNN
// (1 wave, identical math to old knn_kernel), then the sample's two 16-row
// gemm0 MFMA tiles (neighbor idx handed over via __shfl, no nn_idx traffic).
// LDS padded to 84 KiB -> exactly 1 block/CU, 256 blocks = 256 CUs: all
// blocks co-resident regardless of dispatch order => no deadlock, and
// consumers never share a CU with a producer.
#define SMEM_BYTES 86016
#define NCONS_W ((256 - B_) * 4)  // 960 consumer waves

__global__ __launch_bounds__(256, 1) void fused_kernel(
    const float* __restrict__ xyz, const float* __restrict__ points,
    const float* __restrict__ ptn, const ushort_t* __restrict__ wB0,
    const float* __restrict__ bias0, int* __restrict__ pub,
    float* __restrict__ out_newxyz, ushort_t* __restrict__ y0,
    float* __restrict__ stats) {
  __shared__ __align__(16) char smem[SMEM_BYTES];
  int t = threadIdx.x;
  int w = t >> 6, l = t & 63;

  if (blockIdx.x < B_) {
    // ---------------- producer: FPS (identical math to previous fps_kernel)
    float* xyz_s = (float*)smem;                                   // 49152 B
    int* idx_s = (int*)(smem + 49152);                             // 4096 B
    unsigned long long* keys_s = (unsigned long long*)(smem + 53248);  // 2*FPS_W
    int b = blockIdx.x;
    const float* xb = xyz + (size_t)b * N_ * 3;
    for (int i = t; i < N_ * 3; i += FPS_T) xyz_s[i] = xb[i];
    __syncthreads();
    float px[FPS_P], py[FPS_P], pz[FPS_P], dd[FPS_P];
#pragma unroll
    for (int j = 0; j < FPS_P; ++j) {
      int n = t + j * FPS_T;
      px[j] = xyz_s[n * 3 + 0];
      py[j] = xyz_s[n * 3 + 1];
      pz[j] = xyz_s[n * 3 + 2];
      dd[j] = 1e10f;
    }
    int fi = 0;
#pragma unroll 1
    for (int s = 0; s < S_; ++s) {
      if (t == 0) {
        idx_s[s] = fi;
        __hip_atomic_store(&pub[(b << 10) + s], fi + 1, __ATOMIC_RELAXED,
                           __HIP_MEMORY_SCOPE_AGENT);
      }
      float cx = xyz_s[fi * 3 + 0], cy = xyz_s[fi * 3 + 1], cz = xyz_s[fi * 3 + 2];
      float bv = -1.0f;
      int bi = 0;
#pragma unroll
      for (int j = 0; j < FPS_P; ++j) {
        float dx = __fsub_rn(px[j], cx);
        float dy = __fsub_rn(py[j], cy);
        float dz = __fsub_rn(pz[j], cz);
        float d = __fadd_rn(__fadd_rn(__fmul_rn(dx, dx), __fmul_rn(dy, dy)),
                            __fmul_rn(dz, dz));
        d = fminf(dd[j], d);
        dd[j] = d;
        if (d > bv) { bv = d; bi = t + j * FPS_T; }
      }
      unsigned hi = __float_as_uint(bv);
      unsigned lo = (unsigned)(N_ - 1 - bi);
      dpp_max_u64<0x111>(hi, lo);
      dpp_max_u64<0x112>(hi, lo);
      dpp_max_u64<0x114>(hi, lo);
      dpp_max_u64<0x118>(hi, lo);
      dpp_max_u64<0x142>(hi, lo);
      dpp_max_u64<0x143>(hi, lo);
      unsigned whi = (unsigned)__builtin_amdgcn_readlane((int)hi, 63);
      unsigned wlo = (unsigned)__builtin_amdgcn_readlane((int)lo, 63);
      if ((t & 63) == 0)
        keys_s[(s & 1) * FPS_W + (t >> 6)] =
            ((unsigned long long)whi << 32) | wlo;
      __syncthreads();
      unsigned long long m = keys_s[(s & 1) * FPS_W + 0];
#pragma unroll
      for (int ww = 1; ww < FPS_W; ++ww) {
        unsigned long long k = keys_s[(s & 1) * FPS_W + ww];
        m = k > m ? k : m;
      }
      fi = (N_ - 1) - (int)(unsigned)(m & 0xFFFFFFFFULL);
    }
    __syncthreads();
    for (int s = t; s < S_; s += FPS_T) {
      int i = idx_s[s];
      out_newxyz[((size_t)b * S_ + s) * 3 + 0] = xyz_s[i * 3 + 0];
      out_newxyz[((size_t)b * S_ + s) * 3 + 1] = xyz_s[i * 3 + 1];
      out_newxyz[((size_t)b * S_ + s) * 3 + 2] = xyz_s[i * 3 + 2];
    }
    return;
  }

  // ---------------- consumer: per-wave kNN + gemm0
  int n16 = l & 15, quad = l >> 4;
  U4S8 bf0[4][3];
  float b0v[4], ssum[4], ssq[4];
#pragma unroll
  for (int nt = 0; nt < 4; ++nt) {
#pragma unroll
    for (int kc = 0; kc < 3; ++kc)
      bf0[nt][kc].u = *reinterpret_cast<const uint4*>(
          wB0 + (size_t)(nt * 16 + n16) * 96 + kc * 32 + quad * 8);
    b0v[nt] = bias0[nt * 16 + n16];
    ssum[nt] = 0.0f;
    ssq[nt] = 0.0f;
  }
  float* ltw = (float*)(smem + w * (16 * 68 * 4));  // per-wave 4352 B bounce
  int wid = (blockIdx.x - B_) * 4 + w;              // 0..959

#pragma unroll 1
  for (int r = wid; r < B_ * S_; r += NCONS_W) {
    int b = r & 15, s = r >> 4;
    int bs = (b << 10) + s;
    int pv = 0;
    if (l == 0) {
      int tries = 0;
      while ((pv = __hip_atomic_load(&pub[bs], __ATOMIC_RELAXED,
                                     __HIP_MEMORY_SCOPE_AGENT)) == 0) {
        __builtin_amdgcn_s_sleep(32);
        if (++tries > 65536) break;  // visible-failure valve, never trips normally
      }
    }
    pv = __shfl(pv, 0);
    int ci = pv - 1;
    if (ci < 0) ci = 0;  // valve tripped -> wrong-but-safe
    const float* xb = xyz + (size_t)b * N_ * 3;
    const float* pnb = ptn + (size_t)b * N_;
    float sx = xb[ci * 3 + 0], sy = xb[ci * 3 + 1], sz = xb[ci * 3 + 2];
    float nxn = pnb[ci];

    // ---- kNN (identical math to previous knn_kernel) ----
    unsigned u[64];
#pragma unroll
    for (int j = 0; j < 64; ++j) {
      int nn = j * 64 + l;
      float x = xb[nn * 3 + 0], y = xb[nn * 3 + 1], z = xb[nn * 3 + 2];
      float e = __fadd_rn(__fadd_rn(__fmul_rn(sx, x), __fmul_rn(sy, y)),
                          __fmul_rn(sz, z));
      float d = __fadd_rn(__fadd_rn(nxn, pnb[nn]), __fmul_rn(-2.0f, e));
      int sb = __float_as_int(d);
      u[j] = (sb < 0) ? ~((unsigned)sb) : (((unsigned)sb) | 0x80000000u);
    }
    unsigned keep = 0;
#pragma unroll 1
    for (int p = 0; p < K_; ++p) {
      unsigned bv = 0xFFFFFFFFu;
      int bj = 0;
#pragma unroll
      for (int j = 0; j < 64; ++j) {
        if (u[j] < bv) { bv = u[j]; bj = j; }
      }
      unsigned bnn = (unsigned)(bj * 64 + l);
#pragma unroll
      for (int off = 32; off > 0; off >>= 1) {
        unsigned ov = __shfl_down(bv, off);
        unsigned on = __shfl_down(bnn, off);
        if (ov < bv || (ov == bv && on < bnn)) { bv = ov; bnn = on; }
      }
      unsigned gn = __shfl(bnn, 0);
      if (l == p) keep = gn;
      if ((gn & 63u) == (unsigned)l) {
        int gj = gn >> 6;
#pragma unroll
        for (int j = 0; j < 64; ++j)
          if (j == gj) u[j] = 0xFFFFFFFFu;
      }
    }

    // ---- gemm0: two 16-row MFMA tiles for this sample ----
#pragma unroll 1
    for (int t2 = 0; t2 < 2; ++t2) {
      int rb = bs * 32 + t2 * 16;
      int idxr = __shfl((int)keep, t2 * 16 + n16);
      const float* pbase = points + (size_t)b * N_ * 64 + (size_t)idxr * 64;
      U4S8 af[3];
#pragma unroll
      for (int kc = 0; kc < 2; ++kc) {
        float4 va = *reinterpret_cast<const float4*>(pbase + kc * 32 + quad * 8);
        float4 vb = *reinterpret_cast<const float4*>(pbase + kc * 32 + quad * 8 + 4);
        af[kc].u = make_uint4(pkrne(va.x, va.y), pkrne(va.z, va.w),
                              pkrne(vb.x, vb.y), pkrne(vb.z, vb.w));
      }
      if (quad == 0) {
        const float* xb3 = xb + (size_t)idxr * 3;
        float dx = __fsub_rn(xb3[0], sx);
        float dy = __fsub_rn(xb3[1], sy);
        float dz = __fsub_rn(xb3[2], sz);
        af[2].u = make_uint4(pkrne(dx, dy), (unsigned)f2bf(dz), 0u, 0u);
      } else {
        af[2].u = make_uint4(0u, 0u, 0u, 0u);
      }
      floatx4 acc[4];
#pragma unroll
      for (int nt = 0; nt < 4; ++nt) acc[nt] = floatx4{0.f, 0.f, 0.f, 0.f};
#pragma unroll
      for (int kc = 0; kc < 3; ++kc)
#pragma unroll
        for (int nt = 0; nt < 4; ++nt)
          acc[nt] = __builtin_amdgcn_mfma_f32_16x16x32_bf16(
              af[kc].v, bf0[nt][kc].v, acc[nt], 0, 0, 0);
#pragma unroll
      for (int nt = 0; nt < 4; ++nt)
#pragma unroll
        for (int rI = 0; rI < 4; ++rI) {
          float ys = acc[nt][rI] + b0v[nt];
          ssum[nt] += ys;
          ssq[nt] = fmaf(ys, ys, ssq[nt]);
          ltw[(quad * 4 + rI) * 68 + nt * 16 + n16] = ys;
        }
      const float* lrow = ltw + n16 * 68 + quad * 16;
      float4 va = *reinterpret_cast<const float4*>(lrow);
      float4 vb = *reinterpret_cast<const float4*>(lrow + 4);
      float4 vc = *reinterpret_cast<const float4*>(lrow + 8);
      float4 vd = *reinterpret_cast<const float4*>(lrow + 12);
      ushort_t* yo = y0 + (size_t)(rb + n16) * 64 + quad * 16;
      *reinterpret_cast<uint4*>(yo) =
          make_uint4(pkhu(va.x, va.y), pkhu(va.z, va.w), pkhu(vb.x, vb.y), pkhu(vb.z, vb.w));
      *reinterpret_cast<uint4*>(yo + 8) =
          make_uint4(pkhu(vc.x, vc.y), pkhu(vc.z, vc.w), pkhu(vd.x, vd.y), pkhu(vd.z, vd.w));
    }
  }

  // ---- stats flush (once per wave) ----
  float* stp = stats + (size_t)(wid & (NSLOT - 1)) * 64 * 2;
#pragma unroll
  for (int nt = 0; nt < 4; ++nt) {
    float s = ssum[nt], q = ssq[nt];
    s += __shfl_down(s, 16); q += __shfl_down(q, 16);
    s += __shfl_down(s, 32); q += __shfl_down(q, 32);
    if (l < 16) {
      atomicAdd(&stp[(size_t)(nt * 16 + l) * 2 + 0], s);
      atomicAdd(&stp[(size_t)(nt * 16 + l) * 2 + 1], q);
    }
  }
}

// ================================================================ gemm1 (MFMA)
__global__ __launch_bounds__(256) void gemm1_mfma(
    const ushort_t* __restrict__ y0, const float* __restrict__ bnp,
    const ushort_t* __restrict__ wB1, const float* __restrict__ bias1,
    ushort_t* __restrict__ y1, float* __restrict__ stats) {
  __shared__ __align__(16) float lt[4][16 * 68];
  int t = threadIdx.x;
  int w = t >> 6, l = t & 63;
  int n = l & 15, quad = l >> 4;
  U4S8 bf[4][2];
#pragma unroll
  for (int nt = 0; nt < 4; ++nt)
#pragma unroll
    for (int kc = 0; kc < 2; ++kc)
      bf[nt][kc].u = *reinterpret_cast<const uint4*>(
          wB1 + (size_t)(nt * 16 + n) * 64 + kc * 32 + quad * 8);
  float4 scA[2], scB[2], shA[2], shB[2];
#pragma unroll
  for (int kc = 0; kc < 2; ++kc) {
    int cb = kc * 32 + quad * 8;
    scA[kc] = *reinterpret_cast<const float4*>(&bnp[cb]);
    scB[kc] = *reinterpret_cast<const float4*>(&bnp[cb + 4]);
    shA[kc] = *reinterpret_cast<const float4*>(&bnp[64 + cb]);
    shB[kc] = *reinterpret_cast<const float4*>(&bnp[64 + cb + 4]);
  }
  float b1v[4], ssum[4], ssq[4];
#pragma unroll
  for (int nt = 0; nt < 4; ++nt) {
    b1v[nt] = bias1[nt * 16 + n];
    ssum[nt] = 0.0f;
    ssq[nt] = 0.0f;
  }
  int rowbase0 = blockIdx.x * 1024 + w * 256;
  float* ltw = lt[w];
#pragma unroll 1
  for (int tile = 0; tile < 16; ++tile) {
    int rb = rowbase0 + tile * 16;
    U4S8 af[2];
#pragma unroll
    for (int kc = 0; kc < 2; ++kc) {
      uint4 xv = *reinterpret_cast<const uint4*>(
          y0 + (size_t)(rb + n) * 64 + kc * 32 + quad * 8);
      af[kc].u = bn_relu_pack(xv, scA[kc], scB[kc], shA[kc], shB[kc]);
    }
    floatx4 acc[4];
#pragma unroll
    for (int nt = 0; nt < 4; ++nt) acc[nt] = floatx4{0.f, 0.f, 0.f, 0.f};
#pragma unroll
    for (int kc = 0; kc < 2; ++kc)
#pragma unroll
      for (int nt = 0; nt < 4; ++nt)
        acc[nt] = __builtin_amdgcn_mfma_f32_16x16x32_bf16(
            af[kc].v, bf[nt][kc].v, acc[nt], 0, 0, 0);
#pragma unroll
    for (int nt = 0; nt < 4; ++nt)
#pragma unroll
      for (int rI = 0; rI < 4; ++rI) {
        float ys = acc[nt][rI] + b1v[nt];
        ssum[nt] += ys;
        ssq[nt] = fmaf(ys, ys, ssq[nt]);
        ltw[(quad * 4 + rI) * 68 + nt * 16 + n] = ys;
      }
    const float* lrow = ltw + n * 68 + quad * 16;
    float4 va = *reinterpret_cast<const float4*>(lrow);
    float4 vb = *reinterpret_cast<const float4*>(lrow + 4);
    float4 vc = *reinterpret_cast<const float4*>(lrow + 8);
    float4 vd = *reinterpret_cast<const float4*>(lrow + 12);
    ushort_t* yo = y1 + (size_t)(rb + n) * 64 + quad * 16;
    *reinterpret_cast<uint4*>(yo) =
        make_uint4(pkhu(va.x, va.y), pkhu(va.z, va.w), pkhu(vb.x, vb.y), pkhu(vb.z, vb.w));
    *reinterpret_cast<uint4*>(yo + 8) =
        make_uint4(pkhu(vc.x, vc.y), pkhu(vc.z, vc.w), pkhu(vd.x, vd.y), pkhu(vd.z, vd.w));
  }
  float* stp = stats + (size_t)((blockIdx.x * 4 + w) & (NSLOT - 1)) * 64 * 2;
#pragma unroll
  for (int nt = 0; nt < 4; ++nt) {
    float s = ssum[nt], q = ssq[nt];
    s += __shfl_down(s, 16); q += __shfl_down(q, 16);
    s += __shfl_down(s, 32); q += __shfl_down(q, 32);
    if (l < 16) {
      atomicAdd(&stp[(size_t)(nt * 16 + l) * 2 + 0], s);
      atomicAdd(&stp[(size_t)(nt * 16 + l) * 2 + 1], q);
    }
  }
}

// ================================================================ gemm2 (MFMA)
__global__ __launch_bounds__(256) void gemm2_mfma(
    const ushort_t* __restrict__ y1, const float* __restrict__ bnp,
    const ushort_t* __restrict__ wB2, const float* __restrict__ bias2,
    float* __restrict__ stats, float* __restrict__ maxY, float* __restrict__ minY) {
  int t = threadIdx.x;
  int w = t >> 6, l = t & 63;
  int n = l & 15, quad = l >> 4;
  U4S8 bf[8][2];
#pragma unroll
  for (int nt = 0; nt < 8; ++nt)
#pragma unroll
    for (int kc = 0; kc < 2; ++kc)
      bf[nt][kc].u = *reinterpret_cast<const uint4*>(
          wB2 + (size_t)(nt * 16 + n) * 64 + kc * 32 + quad * 8);
  float4 scA[2], scB[2], shA[2], shB[2];
#pragma unroll
  for (int kc = 0; kc < 2; ++kc) {
    int cb = kc * 32 + quad * 8;
    scA[kc] = *reinterpret_cast<const float4*>(&bnp[128 + cb]);
    scB[kc] = *reinterpret_cast<const float4*>(&bnp[128 + cb + 4]);
    shA[kc] = *reinterpret_cast<const float4*>(&bnp[192 + cb]);
    shB[kc] = *reinterpret_cast<const float4*>(&bnp[192 + cb + 4]);
  }
  float b2v[8], ssum[8], ssq[8], mxv[8], mnv[8];
#pragma unroll
  for (int nt = 0; nt < 8; ++nt) {
    b2v[nt] = bias2[nt * 16 + n];
    ssum[nt] = 0.0f;
    ssq[nt] = 0.0f;
    mxv[nt] = -3.4e38f;
    mnv[nt] = 3.4e38f;
  }
  int rowbase0 = blockIdx.x * 1024 + w * 256;
#pragma unroll 1
  for (int tile = 0; tile < 16; ++tile) {
    int rb = rowbase0 + tile * 16;
    U4S8 af[2];
#pragma unroll
    for (int kc = 0; kc < 2; ++kc) {
      uint4 xv = *reinterpret_cast<const uint4*>(
          y1 + (size_t)(rb + n) * 64 + kc * 32 + quad * 8);
      af[kc].u = bn_relu_pack(xv, scA[kc], scB[kc], shA[kc], shB[kc]);
    }
    floatx4 acc[8];
#pragma unroll
    for (int nt = 0; nt < 8; ++nt) acc[nt] = floatx4{0.f, 0.f, 0.f, 0.f};
#pragma unroll
    for (int kc = 0; kc < 2; ++kc)
#pragma unroll
      for (int nt = 0; nt < 8; ++nt)
        acc[nt] = __builtin_amdgcn_mfma_f32_16x16x32_bf16(
            af[kc].v, bf[nt][kc].v, acc[nt], 0, 0, 0);
#pragma unroll
    for (int nt = 0; nt < 8; ++nt)
#pragma unroll
      for (int rI = 0; rI < 4; ++rI) {
        float ya = acc[nt][rI] + b2v[nt];
        ssum[nt] += ya;
        ssq[nt] = fmaf(ya, ya, ssq[nt]);
        mxv[nt] = fmaxf(mxv[nt], ya);
        mnv[nt] = fminf(mnv[nt], ya);
      }
    if (tile & 1) {
      int sidx = (rowbase0 >> 5) + (tile >> 1);
#pragma unroll
      for (int nt = 0; nt < 8; ++nt) {
        float mx = mxv[nt], mn = mnv[nt];
        mx = fmaxf(mx, __shfl_down(mx, 16));
        mn = fminf(mn, __shfl_down(mn, 16));
        mx = fmaxf(mx, __shfl_down(mx, 32));
        mn = fminf(mn, __shfl_down(mn, 32));
        if (l < 16) {
          maxY[(size_t)sidx * 128 + nt * 16 + l] = mx;
          minY[(size_t)sidx * 128 + nt * 16 + l] = mn;
        }
        mxv[nt] = -3.4e38f;
        mnv[nt] = 3.4e38f;
      }
    }
  }
  float* stp = stats + (size_t)((blockIdx.x * 4 + w) & (NSLOT - 1)) * 128 * 2;
#pragma unroll
  for (int nt = 0; nt < 8; ++nt) {
    float s = ssum[nt], q = ssq[nt];
    s += __shfl_down(s, 16); q += __shfl_down(q, 16);
    s += __shfl_down(s, 32); q += __shfl_down(q, 32);
    if (l < 16) {
      atomicAdd(&stp[(size_t)(nt * 16 + l) * 2 + 0], s);
      atomicAdd(&stp[(size_t)(nt * 16 + l) * 2 + 1], q);
    }
  }
}

// ---------------------------------------------------------------- BN finalize
__global__ void bn_finalize(const float* __restrict__ st, int cout,
                            const float* __restrict__ gamma,
                            const float* __restrict__ beta,
                            float* __restrict__ scale, float* __restrict__ shift) {
  int o = threadIdx.x;
  if (o >= cout) return;
  float s = 0.0f, q = 0.0f;
  for (int i = 0; i < NSLOT; ++i) {
    s += st[((size_t)i * cout + o) * 2 + 0];
    q += st[((size_t)i * cout + o) * 2 + 1];
  }
  float mean = s * (1.0f / CNT_F);
  float var = q * (1.0f / CNT_F) - mean * mean;
  float sc = gamma[o] / sqrtf(var + 1e-5f);
  scale[o] = sc;
  shift[o] = beta[o] - mean * sc;
}

// ---------------------------------------------------------------- pooling
__global__ __launch_bounds__(256) void pool_kernel(
    const float* __restrict__ maxY, const float* __restrict__ minY,
    const float* __restrict__ bnp, float* __restrict__ out) {
  __shared__ float tile[128 * 65];
  int b = blockIdx.x >> 4;
  int sbase = (blockIdx.x & 15) * 64;
  int t = threadIdx.x;
#pragma unroll 4
  for (int i = 0; i < 32; ++i) {
    int e = i * 256 + t;
    int sl = e >> 7, o = e & 127;
    float sc = bnp[256 + o], sh = bnp[384 + o];
    size_t g = ((size_t)(b * S_ + sbase + sl)) * 128 + o;
    float v = (sc >= 0.0f) ? maxY[g] : minY[g];
    tile[o * 65 + sl] = fmaxf(fmaf(v, sc, sh), 0.0f);
  }
  __syncthreads();
  int sl = t & 63;
  for (int o2 = t >> 6; o2 < 128; o2 += 4) {
    out[((size_t)(b * 128 + o2)) * S_ + sbase + sl] = tile[o2 * 65 + sl];
  }
}

// ---------------------------------------------------------------- launch
static inline size_t alup(size_t x) { return (x + 255) & ~(size_t)255; }

extern "C" void kernel_launch(void* const* d_in, const int* in_sizes, int n_in,
                              void* d_out, int out_size, void* d_ws, size_t ws_size,
                              hipStream_t stream) {
  (void)in_sizes; (void)n_in; (void)out_size;
  const float* xyz = (const float*)d_in[0];
  const float* points = (const float*)d_in[1];
  const float* w0 = (const float*)d_in[2];
  const float* b0 = (const float*)d_in[3];
  const float* g0 = (const float*)d_in[4];
  const float* be0 = (const float*)d_in[5];
  const float* w1 = (const float*)d_in[6];
  const float* b1 = (const float*)d_in[7];
  const float* g1 = (const float*)d_in[8];
  const float* be1 = (const float*)d_in[9];
  const float* w2 = (const float*)d_in[10];
  const float* b2 = (const float*)d_in[11];
  const float* g2 = (const float*)d_in[12];
  const float* be2 = (const float*)d_in[13];
  float* out_newxyz = (float*)d_out;
  float* out_newpts = out_newxyz + (size_t)B_ * S_ * 3;

  char* p = (char*)d_ws;
  int* pub = (int*)p;     p += alup((size_t)B_ * S_ * 4);
  float* ptn = (float*)p; p += alup((size_t)B_ * N_ * 4);
  float* st0 = (float*)p; p += (size_t)NSLOT * 64 * 2 * 4;
  float* st1 = (float*)p; p += (size_t)NSLOT * 64 * 2 * 4;
  float* st2 = (float*)p; p += (size_t)NSLOT * 128 * 2 * 4;
  float* bnp = (float*)p; p += alup(512 * 4);
  ushort_t* wB0 = (ushort_t*)p; p += alup(64 * 96 * 2);
  ushort_t* wB1 = (ushort_t*)p; p += alup(64 * 64 * 2);
  ushort_t* wB2 = (ushort_t*)p; p += alup(128 * 64 * 2);
  float* maxY = (float*)p; p += (size_t)B_ * S_ * 128 * 4;
  float* minY = (float*)p; p += (size_t)B_ * S_ * 128 * 4;
  ushort_t* y0 = (ushort_t*)p; p += (size_t)RWS * 64 * 2;
  ushort_t* y1 = (ushort_t*)p; p += (size_t)RWS * 64 * 2;
  if ((size_t)(p - (char*)d_ws) > ws_size) return;  // visible failure

  float* sc0 = bnp;       float* sh0 = bnp + 64;
  float* sc1 = bnp + 128; float* sh1 = bnp + 192;
  float* sc2 = bnp + 256; float* sh2 = bnp + 384;

  hipMemsetAsync(st0, 0, (size_t)NSLOT * (64 + 64 + 128) * 2 * 4, stream);
  hipMemsetAsync(pub, 0, (size_t)B_ * S_ * 4, stream);
  prep_all<<<256, 256, 0, stream>>>(xyz, ptn, w0, w1, w2, wB0, wB1, wB2);
  fused_kernel<<<256, 256, 0, stream>>>(
      xyz, points, ptn, wB0, b0, pub, out_newxyz, y0, st0);
  bn_finalize<<<1, 128, 0, stream>>>(st0, 64, g0, be0, sc0, sh0);
  gemm1_mfma<<<RWS / 1024, 256, 0, stream>>>(y0, bnp, wB1, b1, y1, st1);
  bn_finalize<<<1, 128, 0, stream>>>(st1, 64, g1, be1, sc1, sh1);
  gemm2_mfma<<<RWS / 1024, 256, 0, stream>>>(y1, bnp, wB2, b2, st2, maxY, minY);
  bn_finalize<<<1, 128, 0, stream>>>(st2, 128, g2, be2, sc2, sh2);
  pool_kernel<<<B_ * (S_ / 64), 256, 0, stream>>>(maxY, minY, bnp, out_newpts);
}

// Round 2
// 995.651 us; speedup vs baseline: 1.2757x; 1.2056x over previous
//
#include <hip/hip_runtime.h>

#define B_ 16
#define N_ 4096
#define S_ 1024
#define K_ 32
#define NSLOT 128
#define CNT_F 524288.0f   // B*S*K
#define RWS 524288        // total rows = B*S*K

typedef unsigned short ushort_t;
typedef short short8 __attribute__((ext_vector_type(8)));
typedef float floatx4 __attribute__((ext_vector_type(4)));
union U4S8 { uint4 u; short8 v; };

__device__ __forceinline__ ushort_t f2bf(float f) {  // RNE
  unsigned u = __float_as_uint(f);
  unsigned r = (u + 0x7fffu + ((u >> 16) & 1u)) >> 16;
  return (ushort_t)r;
}
__device__ __forceinline__ unsigned pkrne(float a, float b) {
  return (unsigned)f2bf(a) | ((unsigned)f2bf(b) << 16);
}
__device__ __forceinline__ unsigned pkhu(float a, float b) {  // half-up pair
  return ((__float_as_uint(a) + 0x8000u) >> 16) |
         ((__float_as_uint(b) + 0x8000u) & 0xffff0000u);
}

// unpack 8 bf16, apply bn scale/shift + relu, repack as bf16 (half-up)
__device__ __forceinline__ uint4 bn_relu_pack(uint4 xv, float4 sca, float4 scb,
                                              float4 sha, float4 shb) {
  float x0 = __uint_as_float(xv.x << 16);
  float x1 = __uint_as_float(xv.x & 0xffff0000u);
  float x2 = __uint_as_float(xv.y << 16);
  float x3 = __uint_as_float(xv.y & 0xffff0000u);
  float x4 = __uint_as_float(xv.z << 16);
  float x5 = __uint_as_float(xv.z & 0xffff0000u);
  float x6 = __uint_as_float(xv.w << 16);
  float x7 = __uint_as_float(xv.w & 0xffff0000u);
  x0 = fmaxf(fmaf(x0, sca.x, sha.x), 0.0f);
  x1 = fmaxf(fmaf(x1, sca.y, sha.y), 0.0f);
  x2 = fmaxf(fmaf(x2, sca.z, sha.z), 0.0f);
  x3 = fmaxf(fmaf(x3, sca.w, sha.w), 0.0f);
  x4 = fmaxf(fmaf(x4, scb.x, shb.x), 0.0f);
  x5 = fmaxf(fmaf(x5, scb.y, shb.y), 0.0f);
  x6 = fmaxf(fmaf(x6, scb.z, shb.z), 0.0f);
  x7 = fmaxf(fmaf(x7, scb.w, shb.w), 0.0f);
  return make_uint4(pkhu(x0, x1), pkhu(x2, x3), pkhu(x4, x5), pkhu(x6, x7));
}

// ---------------------------------------------------------------- FPS params
#define FPS_T 512
#define FPS_P (N_ / FPS_T)   // 8
#define FPS_W (FPS_T / 64)   // 8

template <int CTRL>
__device__ __forceinline__ void dpp_max_u64(unsigned& hi, unsigned& lo) {
  unsigned h2 = (unsigned)__builtin_amdgcn_update_dpp(0, (int)hi, CTRL, 0xf, 0xf, true);
  unsigned l2 = (unsigned)__builtin_amdgcn_update_dpp(0, (int)lo, CTRL, 0xf, 0xf, true);
  bool take = (h2 > hi) || (h2 == hi && l2 > lo);
  hi = take ? h2 : hi;
  lo = take ? l2 : lo;
}

// ---------------------------------------------------------------- prep (ptnorm + weights)
__global__ __launch_bounds__(256) void prep_all(
    const float* __restrict__ xyz, float* __restrict__ pt,
    const float* __restrict__ w0, const float* __restrict__ w1,
    const float* __restrict__ w2, ushort_t* __restrict__ wB0,
    ushort_t* __restrict__ wB1, ushort_t* __restrict__ wB2) {
  int i = blockIdx.x * 256 + threadIdx.x;  // < 65536 = B*N
  float x = xyz[(size_t)i * 3 + 0];
  float y = xyz[(size_t)i * 3 + 1];
  float z = xyz[(size_t)i * 3 + 2];
  pt[i] = __fadd_rn(__fadd_rn(__fmul_rn(x, x), __fmul_rn(y, y)), __fmul_rn(z, z));
  // wB0: [o][96] = [p-weights(64), xyz-weights(3), zeros(29)]
  if (i < 64 * 96) {
    int o = i / 96, c = i % 96;
    ushort_t v = 0;
    if (c < 64) v = f2bf(w0[o * 67 + 3 + c]);
    else if (c < 67) v = f2bf(w0[o * 67 + (c - 64)]);
    wB0[i] = v;
  }
  if (i < 64 * 64) wB1[i] = f2bf(w1[i]);
  if (i < 128 * 64) wB2[i] = f2bf(w2[i]);
}

// ================================================================ fused
// Blocks 0..15: FPS producer (one per batch, 8 waves), publishing each
// sample's index via device-scope relaxed atomic (value doubles as flag).
// Blocks 16..255: consumer blocks, 8 independent waves each (1920 waves);
// per sample: spin for index, kNN (grouped-tournament argmin + DPP u64
// reduce), then the sample's two 16-row gemm0 MFMA tiles.
// LDS padded to 84 KiB -> exactly 1 block/CU, 256 blocks = 256 CUs: all
// blocks co-resident regardless of dispatch order => no deadlock; consumer
// waves get 2/SIMD latency hiding; producers keep exclusive CUs.
#define SMEM_BYTES 86016
#define NCONS_W ((256 - B_) * 8)  // 1920 consumer waves

__global__ __launch_bounds__(512, 2) void fused_kernel(
    const float* __restrict__ xyz, const float* __restrict__ points,
    const float* __restrict__ ptn, const ushort_t* __restrict__ wB0,
    const float* __restrict__ bias0, int* __restrict__ pub,
    float* __restrict__ out_newxyz, ushort_t* __restrict__ y0,
    float* __restrict__ stats) {
  __shared__ __align__(16) char smem[SMEM_BYTES];
  int t = threadIdx.x;
  int w = t >> 6, l = t & 63;

  if (blockIdx.x < B_) {
    // ---------------- producer: FPS (8 waves, same math)
    float* xyz_s = (float*)smem;                                   // 49152 B
    int* idx_s = (int*)(smem + 49152);                             // 4096 B
    unsigned long long* keys_s = (unsigned long long*)(smem + 53248);  // 2*FPS_W
    int b = blockIdx.x;
    const float* xb = xyz + (size_t)b * N_ * 3;
    for (int i = t; i < N_ * 3; i += FPS_T) xyz_s[i] = xb[i];
    __syncthreads();
    float px[FPS_P], py[FPS_P], pz[FPS_P], dd[FPS_P];
#pragma unroll
    for (int j = 0; j < FPS_P; ++j) {
      int n = t + j * FPS_T;
      px[j] = xyz_s[n * 3 + 0];
      py[j] = xyz_s[n * 3 + 1];
      pz[j] = xyz_s[n * 3 + 2];
      dd[j] = 1e10f;
    }
    int fi = 0;
#pragma unroll 1
    for (int s = 0; s < S_; ++s) {
      if (t == 0) {
        idx_s[s] = fi;
        __hip_atomic_store(&pub[(b << 10) + s], fi + 1, __ATOMIC_RELAXED,
                           __HIP_MEMORY_SCOPE_AGENT);
      }
      float cx = xyz_s[fi * 3 + 0], cy = xyz_s[fi * 3 + 1], cz = xyz_s[fi * 3 + 2];
      float bv = -1.0f;
      int bi = 0;
#pragma unroll
      for (int j = 0; j < FPS_P; ++j) {
        float dx = __fsub_rn(px[j], cx);
        float dy = __fsub_rn(py[j], cy);
        float dz = __fsub_rn(pz[j], cz);
        float d = __fadd_rn(__fadd_rn(__fmul_rn(dx, dx), __fmul_rn(dy, dy)),
                            __fmul_rn(dz, dz));
        d = fminf(dd[j], d);
        dd[j] = d;
        if (d > bv) { bv = d; bi = t + j * FPS_T; }
      }
      unsigned hi = __float_as_uint(bv);
      unsigned lo = (unsigned)(N_ - 1 - bi);
      dpp_max_u64<0x111>(hi, lo);
      dpp_max_u64<0x112>(hi, lo);
      dpp_max_u64<0x114>(hi, lo);
      dpp_max_u64<0x118>(hi, lo);
      dpp_max_u64<0x142>(hi, lo);
      dpp_max_u64<0x143>(hi, lo);
      unsigned whi = (unsigned)__builtin_amdgcn_readlane((int)hi, 63);
      unsigned wlo = (unsigned)__builtin_amdgcn_readlane((int)lo, 63);
      if ((t & 63) == 0)
        keys_s[(s & 1) * FPS_W + (t >> 6)] =
            ((unsigned long long)whi << 32) | wlo;
      __syncthreads();
      unsigned long long m = keys_s[(s & 1) * FPS_W + 0];
#pragma unroll
      for (int ww = 1; ww < FPS_W; ++ww) {
        unsigned long long k = keys_s[(s & 1) * FPS_W + ww];
        m = k > m ? k : m;
      }
      fi = (N_ - 1) - (int)(unsigned)(m & 0xFFFFFFFFULL);
    }
    __syncthreads();
    for (int s = t; s < S_; s += FPS_T) {
      int i = idx_s[s];
      out_newxyz[((size_t)b * S_ + s) * 3 + 0] = xyz_s[i * 3 + 0];
      out_newxyz[((size_t)b * S_ + s) * 3 + 1] = xyz_s[i * 3 + 1];
      out_newxyz[((size_t)b * S_ + s) * 3 + 2] = xyz_s[i * 3 + 2];
    }
    return;
  }

  // ---------------- consumer: per-wave kNN + gemm0
  int n16 = l & 15, quad = l >> 4;
  U4S8 bf0[4][3];
  float b0v[4], ssum[4], ssq[4];
#pragma unroll
  for (int nt = 0; nt < 4; ++nt) {
#pragma unroll
    for (int kc = 0; kc < 3; ++kc)
      bf0[nt][kc].u = *reinterpret_cast<const uint4*>(
          wB0 + (size_t)(nt * 16 + n16) * 96 + kc * 32 + quad * 8);
    b0v[nt] = bias0[nt * 16 + n16];
    ssum[nt] = 0.0f;
    ssq[nt] = 0.0f;
  }
  float* ltw = (float*)(smem + w * (16 * 68 * 4));  // per-wave 4352 B bounce
  int wid = (blockIdx.x - B_) * 8 + w;              // 0..1919

#pragma unroll 1
  for (int r = wid; r < B_ * S_; r += NCONS_W) {
    int b = r & 15, s = r >> 4;
    int bs = (b << 10) + s;
    int pv = 0;
    if (l == 0) {
      int tries = 0;
      while ((pv = __hip_atomic_load(&pub[bs], __ATOMIC_RELAXED,
                                     __HIP_MEMORY_SCOPE_AGENT)) == 0) {
        __builtin_amdgcn_s_sleep(32);
        if (++tries > 65536) break;  // visible-failure valve, never trips normally
      }
    }
    pv = __shfl(pv, 0);
    int ci = pv - 1;
    if (ci < 0) ci = 0;  // valve tripped -> wrong-but-safe
    const float* xb = xyz + (size_t)b * N_ * 3;
    const float* pnb = ptn + (size_t)b * N_;
    float sx = xb[ci * 3 + 0], sy = xb[ci * 3 + 1], sz = xb[ci * 3 + 2];
    float nxn = pnb[ci];

    // ---- kNN distances (identical math) ----
    unsigned u[64];
#pragma unroll
    for (int j = 0; j < 64; ++j) {
      int nn = j * 64 + l;
      float x = xb[nn * 3 + 0], y = xb[nn * 3 + 1], z = xb[nn * 3 + 2];
      float e = __fadd_rn(__fadd_rn(__fmul_rn(sx, x), __fmul_rn(sy, y)),
                          __fmul_rn(sz, z));
      float d = __fadd_rn(__fadd_rn(nxn, pnb[nn]), __fmul_rn(-2.0f, e));
      int sb = __float_as_int(d);
      u[j] = (sb < 0) ? ~((unsigned)sb) : (((unsigned)sb) | 0x80000000u);
    }
    // ---- top-K selection: grouped tournament + DPP u64 min-reduce ----
    unsigned keep = 0;
#pragma unroll 1
    for (int p = 0; p < K_; ++p) {
      // per-lane argmin over u[0..63], lowest j wins ties (strict <, left-kept)
      unsigned gv[8], gj_[8];
#pragma unroll
      for (int g = 0; g < 8; ++g) {
        unsigned bv = u[g * 8];
        unsigned bj = (unsigned)(g * 8);
#pragma unroll
        for (int j2 = 1; j2 < 8; ++j2) {
          unsigned uu = u[g * 8 + j2];
          bool tk = uu < bv;
          bv = tk ? uu : bv;
          bj = tk ? (unsigned)(g * 8 + j2) : bj;
        }
        gv[g] = bv;
        gj_[g] = bj;
      }
#pragma unroll
      for (int st = 4; st >= 1; st >>= 1)
#pragma unroll
        for (int i2 = 0; i2 < 4; ++i2) {
          if (i2 < st) {
            bool tk = gv[i2 + st] < gv[i2];  // tie -> keep left (lower j)
            gv[i2] = tk ? gv[i2 + st] : gv[i2];
            gj_[i2] = tk ? gj_[i2 + st] : gj_[i2];
          }
        }
      // wave min on (value, global-idx): max-reduce of inverted keys via DPP
      unsigned hi = ~gv[0];
      unsigned lo = ~(gj_[0] * 64u + (unsigned)l);
      dpp_max_u64<0x111>(hi, lo);
      dpp_max_u64<0x112>(hi, lo);
      dpp_max_u64<0x114>(hi, lo);
      dpp_max_u64<0x118>(hi, lo);
      dpp_max_u64<0x142>(hi, lo);
      dpp_max_u64<0x143>(hi, lo);
      unsigned wlo = (unsigned)__builtin_amdgcn_readlane((int)lo, 63);
      unsigned gn = ~wlo;  // global index of winner (min value, then min idx)
      if (l == p) keep = gn;
      if ((gn & 63u) == (unsigned)l) {
        int gj = (int)(gn >> 6);
#pragma unroll
        for (int j = 0; j < 64; ++j)
          if (j == gj) u[j] = 0xFFFFFFFFu;
      }
    }

    // ---- gemm0: two 16-row MFMA tiles for this sample ----
#pragma unroll 1
    for (int t2 = 0; t2 < 2; ++t2) {
      int rb = bs * 32 + t2 * 16;
      int idxr = __shfl((int)keep, t2 * 16 + n16);
      const float* pbase = points + (size_t)b * N_ * 64 + (size_t)idxr * 64;
      U4S8 af[3];
#pragma unroll
      for (int kc = 0; kc < 2; ++kc) {
        float4 va = *reinterpret_cast<const float4*>(pbase + kc * 32 + quad * 8);
        float4 vb = *reinterpret_cast<const float4*>(pbase + kc * 32 + quad * 8 + 4);
        af[kc].u = make_uint4(pkrne(va.x, va.y), pkrne(va.z, va.w),
                              pkrne(vb.x, vb.y), pkrne(vb.z, vb.w));
      }
      if (quad == 0) {
        const float* xb3 = xb + (size_t)idxr * 3;
        float dx = __fsub_rn(xb3[0], sx);
        float dy = __fsub_rn(xb3[1], sy);
        float dz = __fsub_rn(xb3[2], sz);
        af[2].u = make_uint4(pkrne(dx, dy), (unsigned)f2bf(dz), 0u, 0u);
      } else {
        af[2].u = make_uint4(0u, 0u, 0u, 0u);
      }
      floatx4 acc[4];
#pragma unroll
      for (int nt = 0; nt < 4; ++nt) acc[nt] = floatx4{0.f, 0.f, 0.f, 0.f};
#pragma unroll
      for (int kc = 0; kc < 3; ++kc)
#pragma unroll
        for (int nt = 0; nt < 4; ++nt)
          acc[nt] = __builtin_amdgcn_mfma_f32_16x16x32_bf16(
              af[kc].v, bf0[nt][kc].v, acc[nt], 0, 0, 0);
#pragma unroll
      for (int nt = 0; nt < 4; ++nt)
#pragma unroll
        for (int rI = 0; rI < 4; ++rI) {
          float ys = acc[nt][rI] + b0v[nt];
          ssum[nt] += ys;
          ssq[nt] = fmaf(ys, ys, ssq[nt]);
          ltw[(quad * 4 + rI) * 68 + nt * 16 + n16] = ys;
        }
      const float* lrow = ltw + n16 * 68 + quad * 16;
      float4 va = *reinterpret_cast<const float4*>(lrow);
      float4 vb = *reinterpret_cast<const float4*>(lrow + 4);
      float4 vc = *reinterpret_cast<const float4*>(lrow + 8);
      float4 vd = *reinterpret_cast<const float4*>(lrow + 12);
      ushort_t* yo = y0 + (size_t)(rb + n16) * 64 + quad * 16;
      *reinterpret_cast<uint4*>(yo) =
          make_uint4(pkhu(va.x, va.y), pkhu(va.z, va.w), pkhu(vb.x, vb.y), pkhu(vb.z, vb.w));
      *reinterpret_cast<uint4*>(yo + 8) =
          make_uint4(pkhu(vc.x, vc.y), pkhu(vc.z, vc.w), pkhu(vd.x, vd.y), pkhu(vd.z, vd.w));
    }
  }

  // ---- stats flush (once per wave) ----
  float* stp = stats + (size_t)(wid & (NSLOT - 1)) * 64 * 2;
#pragma unroll
  for (int nt = 0; nt < 4; ++nt) {
    float s = ssum[nt], q = ssq[nt];
    s += __shfl_down(s, 16); q += __shfl_down(q, 16);
    s += __shfl_down(s, 32); q += __shfl_down(q, 32);
    if (l < 16) {
      atomicAdd(&stp[(size_t)(nt * 16 + l) * 2 + 0], s);
      atomicAdd(&stp[(size_t)(nt * 16 + l) * 2 + 1], q);
    }
  }
}

// ================================================================ gemm1 (MFMA)
__global__ __launch_bounds__(256) void gemm1_mfma(
    const ushort_t* __restrict__ y0, const float* __restrict__ bnp,
    const ushort_t* __restrict__ wB1, const float* __restrict__ bias1,
    ushort_t* __restrict__ y1, float* __restrict__ stats) {
  __shared__ __align__(16) float lt[4][16 * 68];
  int t = threadIdx.x;
  int w = t >> 6, l = t & 63;
  int n = l & 15, quad = l >> 4;
  U4S8 bf[4][2];
#pragma unroll
  for (int nt = 0; nt < 4; ++nt)
#pragma unroll
    for (int kc = 0; kc < 2; ++kc)
      bf[nt][kc].u = *reinterpret_cast<const uint4*>(
          wB1 + (size_t)(nt * 16 + n) * 64 + kc * 32 + quad * 8);
  float4 scA[2], scB[2], shA[2], shB[2];
#pragma unroll
  for (int kc = 0; kc < 2; ++kc) {
    int cb = kc * 32 + quad * 8;
    scA[kc] = *reinterpret_cast<const float4*>(&bnp[cb]);
    scB[kc] = *reinterpret_cast<const float4*>(&bnp[cb + 4]);
    shA[kc] = *reinterpret_cast<const float4*>(&bnp[64 + cb]);
    shB[kc] = *reinterpret_cast<const float4*>(&bnp[64 + cb + 4]);
  }
  float b1v[4], ssum[4], ssq[4];
#pragma unroll
  for (int nt = 0; nt < 4; ++nt) {
    b1v[nt] = bias1[nt * 16 + n];
    ssum[nt] = 0.0f;
    ssq[nt] = 0.0f;
  }
  int rowbase0 = blockIdx.x * 1024 + w * 256;
  float* ltw = lt[w];
#pragma unroll 1
  for (int tile = 0; tile < 16; ++tile) {
    int rb = rowbase0 + tile * 16;
    U4S8 af[2];
#pragma unroll
    for (int kc = 0; kc < 2; ++kc) {
      uint4 xv = *reinterpret_cast<const uint4*>(
          y0 + (size_t)(rb + n) * 64 + kc * 32 + quad * 8);
      af[kc].u = bn_relu_pack(xv, scA[kc], scB[kc], shA[kc], shB[kc]);
    }
    floatx4 acc[4];
#pragma unroll
    for (int nt = 0; nt < 4; ++nt) acc[nt] = floatx4{0.f, 0.f, 0.f, 0.f};
#pragma unroll
    for (int kc = 0; kc < 2; ++kc)
#pragma unroll
      for (int nt = 0; nt < 4; ++nt)
        acc[nt] = __builtin_amdgcn_mfma_f32_16x16x32_bf16(
            af[kc].v, bf[nt][kc].v, acc[nt], 0, 0, 0);
#pragma unroll
    for (int nt = 0; nt < 4; ++nt)
#pragma unroll
      for (int rI = 0; rI < 4; ++rI) {
        float ys = acc[nt][rI] + b1v[nt];
        ssum[nt] += ys;
        ssq[nt] = fmaf(ys, ys, ssq[nt]);
        ltw[(quad * 4 + rI) * 68 + nt * 16 + n] = ys;
      }
    const float* lrow = ltw + n * 68 + quad * 16;
    float4 va = *reinterpret_cast<const float4*>(lrow);
    float4 vb = *reinterpret_cast<const float4*>(lrow + 4);
    float4 vc = *reinterpret_cast<const float4*>(lrow + 8);
    float4 vd = *reinterpret_cast<const float4*>(lrow + 12);
    ushort_t* yo = y1 + (size_t)(rb + n) * 64 + quad * 16;
    *reinterpret_cast<uint4*>(yo) =
        make_uint4(pkhu(va.x, va.y), pkhu(va.z, va.w), pkhu(vb.x, vb.y), pkhu(vb.z, vb.w));
    *reinterpret_cast<uint4*>(yo + 8) =
        make_uint4(pkhu(vc.x, vc.y), pkhu(vc.z, vc.w), pkhu(vd.x, vd.y), pkhu(vd.z, vd.w));
  }
  float* stp = stats + (size_t)((blockIdx.x * 4 + w) & (NSLOT - 1)) * 64 * 2;
#pragma unroll
  for (int nt = 0; nt < 4; ++nt) {
    float s = ssum[nt], q = ssq[nt];
    s += __shfl_down(s, 16); q += __shfl_down(q, 16);
    s += __shfl_down(s, 32); q += __shfl_down(q, 32);
    if (l < 16) {
      atomicAdd(&stp[(size_t)(nt * 16 + l) * 2 + 0], s);
      atomicAdd(&stp[(size_t)(nt * 16 + l) * 2 + 1], q);
    }
  }
}

// ================================================================ gemm2 (MFMA)
__global__ __launch_bounds__(256) void gemm2_mfma(
    const ushort_t* __restrict__ y1, const float* __restrict__ bnp,
    const ushort_t* __restrict__ wB2, const float* __restrict__ bias2,
    float* __restrict__ stats, float* __restrict__ maxY, float* __restrict__ minY) {
  int t = threadIdx.x;
  int w = t >> 6, l = t & 63;
  int n = l & 15, quad = l >> 4;
  U4S8 bf[8][2];
#pragma unroll
  for (int nt = 0; nt < 8; ++nt)
#pragma unroll
    for (int kc = 0; kc < 2; ++kc)
      bf[nt][kc].u = *reinterpret_cast<const uint4*>(
          wB2 + (size_t)(nt * 16 + n) * 64 + kc * 32 + quad * 8);
  float4 scA[2], scB[2], shA[2], shB[2];
#pragma unroll
  for (int kc = 0; kc < 2; ++kc) {
    int cb = kc * 32 + quad * 8;
    scA[kc] = *reinterpret_cast<const float4*>(&bnp[128 + cb]);
    scB[kc] = *reinterpret_cast<const float4*>(&bnp[128 + cb + 4]);
    shA[kc] = *reinterpret_cast<const float4*>(&bnp[192 + cb]);
    shB[kc] = *reinterpret_cast<const float4*>(&bnp[192 + cb + 4]);
  }
  float b2v[8], ssum[8], ssq[8], mxv[8], mnv[8];
#pragma unroll
  for (int nt = 0; nt < 8; ++nt) {
    b2v[nt] = bias2[nt * 16 + n];
    ssum[nt] = 0.0f;
    ssq[nt] = 0.0f;
    mxv[nt] = -3.4e38f;
    mnv[nt] = 3.4e38f;
  }
  int rowbase0 = blockIdx.x * 1024 + w * 256;
#pragma unroll 1
  for (int tile = 0; tile < 16; ++tile) {
    int rb = rowbase0 + tile * 16;
    U4S8 af[2];
#pragma unroll
    for (int kc = 0; kc < 2; ++kc) {
      uint4 xv = *reinterpret_cast<const uint4*>(
          y1 + (size_t)(rb + n) * 64 + kc * 32 + quad * 8);
      af[kc].u = bn_relu_pack(xv, scA[kc], scB[kc], shA[kc], shB[kc]);
    }
    floatx4 acc[8];
#pragma unroll
    for (int nt = 0; nt < 8; ++nt) acc[nt] = floatx4{0.f, 0.f, 0.f, 0.f};
#pragma unroll
    for (int kc = 0; kc < 2; ++kc)
#pragma unroll
      for (int nt = 0; nt < 8; ++nt)
        acc[nt] = __builtin_amdgcn_mfma_f32_16x16x32_bf16(
            af[kc].v, bf[nt][kc].v, acc[nt], 0, 0, 0);
#pragma unroll
    for (int nt = 0; nt < 8; ++nt)
#pragma unroll
      for (int rI = 0; rI < 4; ++rI) {
        float ya = acc[nt][rI] + b2v[nt];
        ssum[nt] += ya;
        ssq[nt] = fmaf(ya, ya, ssq[nt]);
        mxv[nt] = fmaxf(mxv[nt], ya);
        mnv[nt] = fminf(mnv[nt], ya);
      }
    if (tile & 1) {
      int sidx = (rowbase0 >> 5) + (tile >> 1);
#pragma unroll
      for (int nt = 0; nt < 8; ++nt) {
        float mx = mxv[nt], mn = mnv[nt];
        mx = fmaxf(mx, __shfl_down(mx, 16));
        mn = fminf(mn, __shfl_down(mn, 16));
        mx = fmaxf(mx, __shfl_down(mx, 32));
        mn = fminf(mn, __shfl_down(mn, 32));
        if (l < 16) {
          maxY[(size_t)sidx * 128 + nt * 16 + l] = mx;
          minY[(size_t)sidx * 128 + nt * 16 + l] = mn;
        }
        mxv[nt] = -3.4e38f;
        mnv[nt] = 3.4e38f;
      }
    }
  }
  float* stp = stats + (size_t)((blockIdx.x * 4 + w) & (NSLOT - 1)) * 128 * 2;
#pragma unroll
  for (int nt = 0; nt < 8; ++nt) {
    float s = ssum[nt], q = ssq[nt];
    s += __shfl_down(s, 16); q += __shfl_down(q, 16);
    s += __shfl_down(s, 32); q += __shfl_down(q, 32);
    if (l < 16) {
      atomicAdd(&stp[(size_t)(nt * 16 + l) * 2 + 0], s);
      atomicAdd(&stp[(size_t)(nt * 16 + l) * 2 + 1], q);
    }
  }
}

// ---------------------------------------------------------------- BN finalize
__global__ void bn_finalize(const float* __restrict__ st, int cout,
                            const float* __restrict__ gamma,
                            const float* __restrict__ beta,
                            float* __restrict__ scale, float* __restrict__ shift) {
  int o = threadIdx.x;
  if (o >= cout) return;
  float s = 0.0f, q = 0.0f;
  for (int i = 0; i < NSLOT; ++i) {
    s += st[((size_t)i * cout + o) * 2 + 0];
    q += st[((size_t)i * cout + o) * 2 + 1];
  }
  float mean = s * (1.0f / CNT_F);
  float var = q * (1.0f / CNT_F) - mean * mean;
  float sc = gamma[o] / sqrtf(var + 1e-5f);
  scale[o] = sc;
  shift[o] = beta[o] - mean * sc;
}

// ---------------------------------------------------------------- pooling
__global__ __launch_bounds__(256) void pool_kernel(
    const float* __restrict__ maxY, const float* __restrict__ minY,
    const float* __restrict__ bnp, float* __restrict__ out) {
  __shared__ float tile[128 * 65];
  int b = blockIdx.x >> 4;
  int sbase = (blockIdx.x & 15) * 64;
  int t = threadIdx.x;
#pragma unroll 4
  for (int i = 0; i < 32; ++i) {
    int e = i * 256 + t;
    int sl = e >> 7, o = e & 127;
    float sc = bnp[256 + o], sh = bnp[384 + o];
    size_t g = ((size_t)(b * S_ + sbase + sl)) * 128 + o;
    float v = (sc >= 0.0f) ? maxY[g] : minY[g];
    tile[o * 65 + sl] = fmaxf(fmaf(v, sc, sh), 0.0f);
  }
  __syncthreads();
  int sl = t & 63;
  for (int o2 = t >> 6; o2 < 128; o2 += 4) {
    out[((size_t)(b * 128 + o2)) * S_ + sbase + sl] = tile[o2 * 65 + sl];
  }
}

// ---------------------------------------------------------------- launch
static inline size_t alup(size_t x) { return (x + 255) & ~(size_t)255; }

extern "C" void kernel_launch(void* const* d_in, const int* in_sizes, int n_in,
                              void* d_out, int out_size, void* d_ws, size_t ws_size,
                              hipStream_t stream) {
  (void)in_sizes; (void)n_in; (void)out_size;
  const float* xyz = (const float*)d_in[0];
  const float* points = (const float*)d_in[1];
  const float* w0 = (const float*)d_in[2];
  const float* b0 = (const float*)d_in[3];
  const float* g0 = (const float*)d_in[4];
  const float* be0 = (const float*)d_in[5];
  const float* w1 = (const float*)d_in[6];
  const float* b1 = (const float*)d_in[7];
  const float* g1 = (const float*)d_in[8];
  const float* be1 = (const float*)d_in[9];
  const float* w2 = (const float*)d_in[10];
  const float* b2 = (const float*)d_in[11];
  const float* g2 = (const float*)d_in[12];
  const float* be2 = (const float*)d_in[13];
  float* out_newxyz = (float*)d_out;
  float* out_newpts = out_newxyz + (size_t)B_ * S_ * 3;

  char* p = (char*)d_ws;
  int* pub = (int*)p;     p += alup((size_t)B_ * S_ * 4);
  float* ptn = (float*)p; p += alup((size_t)B_ * N_ * 4);
  float* st0 = (float*)p; p += (size_t)NSLOT * 64 * 2 * 4;
  float* st1 = (float*)p; p += (size_t)NSLOT * 64 * 2 * 4;
  float* st2 = (float*)p; p += (size_t)NSLOT * 128 * 2 * 4;
  float* bnp = (float*)p; p += alup(512 * 4);
  ushort_t* wB0 = (ushort_t*)p; p += alup(64 * 96 * 2);
  ushort_t* wB1 = (ushort_t*)p; p += alup(64 * 64 * 2);
  ushort_t* wB2 = (ushort_t*)p; p += alup(128 * 64 * 2);
  float* maxY = (float*)p; p += (size_t)B_ * S_ * 128 * 4;
  float* minY = (float*)p; p += (size_t)B_ * S_ * 128 * 4;
  ushort_t* y0 = (ushort_t*)p; p += (size_t)RWS * 64 * 2;
  ushort_t* y1 = (ushort_t*)p; p += (size_t)RWS * 64 * 2;
  if ((size_t)(p - (char*)d_ws) > ws_size) return;  // visible failure

  float* sc0 = bnp;       float* sh0 = bnp + 64;
  float* sc1 = bnp + 128; float* sh1 = bnp + 192;
  float* sc2 = bnp + 256; float* sh2 = bnp + 384;

  hipMemsetAsync(st0, 0, (size_t)NSLOT * (64 + 64 + 128) * 2 * 4, stream);
  hipMemsetAsync(pub, 0, (size_t)B_ * S_ * 4, stream);
  prep_all<<<256, 256, 0, stream>>>(xyz, ptn, w0, w1, w2, wB0, wB1, wB2);
  fused_kernel<<<256, 512, 0, stream>>>(
      xyz, points, ptn, wB0, b0, pub, out_newxyz, y0, st0);
  bn_finalize<<<1, 128, 0, stream>>>(st0, 64, g0, be0, sc0, sh0);
  gemm1_mfma<<<RWS / 1024, 256, 0, stream>>>(y0, bnp, wB1, b1, y1, st1);
  bn_finalize<<<1, 128, 0, stream>>>(st1, 64, g1, be1, sc1, sh1);
  gemm2_mfma<<<RWS / 1024, 256, 0, stream>>>(y1, bnp, wB2, b2, st2, maxY, minY);
  bn_finalize<<<1, 128, 0, stream>>>(st2, 128, g2, be2, sc2, sh2);
  pool_kernel<<<B_ * (S_ / 64), 256, 0, stream>>>(maxY, minY, bnp, out_newpts);
}

// Round 3
// 995.637 us; speedup vs baseline: 1.2757x; 1.0000x over previous
//
#include <hip/hip_runtime.h>

#define B_ 16
#define N_ 4096
#define S_ 1024
#define K_ 32
#define NSLOT 128
#define CNT_F 524288.0f   // B*S*K
#define RWS 524288        // total rows = B*S*K

typedef unsigned short ushort_t;
typedef short short8 __attribute__((ext_vector_type(8)));
typedef float floatx4 __attribute__((ext_vector_type(4)));
union U4S8 { uint4 u; short8 v; };

__device__ __forceinline__ ushort_t f2bf(float f) {  // RNE
  unsigned u = __float_as_uint(f);
  unsigned r = (u + 0x7fffu + ((u >> 16) & 1u)) >> 16;
  return (ushort_t)r;
}
__device__ __forceinline__ unsigned pkrne(float a, float b) {
  return (unsigned)f2bf(a) | ((unsigned)f2bf(b) << 16);
}
__device__ __forceinline__ unsigned pkhu(float a, float b) {  // half-up pair
  return ((__float_as_uint(a) + 0x8000u) >> 16) |
         ((__float_as_uint(b) + 0x8000u) & 0xffff0000u);
}

// unpack 8 bf16, apply bn scale/shift + relu, repack as bf16 (half-up)
__device__ __forceinline__ uint4 bn_relu_pack(uint4 xv, float4 sca, float4 scb,
                                              float4 sha, float4 shb) {
  float x0 = __uint_as_float(xv.x << 16);
  float x1 = __uint_as_float(xv.x & 0xffff0000u);
  float x2 = __uint_as_float(xv.y << 16);
  float x3 = __uint_as_float(xv.y & 0xffff0000u);
  float x4 = __uint_as_float(xv.z << 16);
  float x5 = __uint_as_float(xv.z & 0xffff0000u);
  float x6 = __uint_as_float(xv.w << 16);
  float x7 = __uint_as_float(xv.w & 0xffff0000u);
  x0 = fmaxf(fmaf(x0, sca.x, sha.x), 0.0f);
  x1 = fmaxf(fmaf(x1, sca.y, sha.y), 0.0f);
  x2 = fmaxf(fmaf(x2, sca.z, sha.z), 0.0f);
  x3 = fmaxf(fmaf(x3, sca.w, sha.w), 0.0f);
  x4 = fmaxf(fmaf(x4, scb.x, shb.x), 0.0f);
  x5 = fmaxf(fmaf(x5, scb.y, shb.y), 0.0f);
  x6 = fmaxf(fmaf(x6, scb.z, shb.z), 0.0f);
  x7 = fmaxf(fmaf(x7, scb.w, shb.w), 0.0f);
  return make_uint4(pkhu(x0, x1), pkhu(x2, x3), pkhu(x4, x5), pkhu(x6, x7));
}

// ---------------------------------------------------------------- FPS params
#define FPS_T 512
#define FPS_P (N_ / FPS_T)   // 8
#define FPS_W (FPS_T / 64)   // 8

template <int CTRL>
__device__ __forceinline__ void dpp_max_u64(unsigned& hi, unsigned& lo) {
  unsigned h2 = (unsigned)__builtin_amdgcn_update_dpp(0, (int)hi, CTRL, 0xf, 0xf, true);
  unsigned l2 = (unsigned)__builtin_amdgcn_update_dpp(0, (int)lo, CTRL, 0xf, 0xf, true);
  bool take = (h2 > hi) || (h2 == hi && l2 > lo);
  hi = take ? h2 : hi;
  lo = take ? l2 : lo;
}

// ---------------------------------------------------------------- prep (ptnorm + weights)
__global__ __launch_bounds__(256) void prep_all(
    const float* __restrict__ xyz, float* __restrict__ pt,
    const float* __restrict__ w0, const float* __restrict__ w1,
    const float* __restrict__ w2, ushort_t* __restrict__ wB0,
    ushort_t* __restrict__ wB1, ushort_t* __restrict__ wB2) {
  int i = blockIdx.x * 256 + threadIdx.x;  // < 65536 = B*N
  float x = xyz[(size_t)i * 3 + 0];
  float y = xyz[(size_t)i * 3 + 1];
  float z = xyz[(size_t)i * 3 + 2];
  pt[i] = __fadd_rn(__fadd_rn(__fmul_rn(x, x), __fmul_rn(y, y)), __fmul_rn(z, z));
  // wB0: [o][96] = [p-weights(64), xyz-weights(3), zeros(29)]
  if (i < 64 * 96) {
    int o = i / 96, c = i % 96;
    ushort_t v = 0;
    if (c < 64) v = f2bf(w0[o * 67 + 3 + c]);
    else if (c < 67) v = f2bf(w0[o * 67 + (c - 64)]);
    wB0[i] = v;
  }
  if (i < 64 * 64) wB1[i] = f2bf(w1[i]);
  if (i < 128 * 64) wB2[i] = f2bf(w2[i]);
}

// ================================================================ fused
// Blocks 0..15: FPS producer (one per batch, 8 waves), publishing each
// sample's index via device-scope relaxed atomic (value doubles as flag).
// Blocks 16..255: consumer blocks, 8 independent waves each (1920 waves);
// per sample: spin for index, kNN (grouped-tournament argmin + DPP u64
// reduce), then the sample's two 16-row gemm0 MFMA tiles.
// LDS padded to 84 KiB -> exactly 1 block/CU, 256 blocks = 256 CUs.
// __launch_bounds__(512,1): VGPR cap 512 -> compiler allocates ~232 and the
// consumer u[64]/fragments stay register-resident (launch_bounds(512,2)
// capped VGPR at 128 and spilled ~720 MB of scratch traffic per dispatch).
// VGPR<=256 still yields 2 waves/SIMD for the single resident block.
#define SMEM_BYTES 86016
#define NCONS_W ((256 - B_) * 8)  // 1920 consumer waves

__global__ __launch_bounds__(512, 1) void fused_kernel(
    const float* __restrict__ xyz, const float* __restrict__ points,
    const float* __restrict__ ptn, const ushort_t* __restrict__ wB0,
    const float* __restrict__ bias0, int* __restrict__ pub,
    float* __restrict__ out_newxyz, ushort_t* __restrict__ y0,
    float* __restrict__ stats) {
  __shared__ __align__(16) char smem[SMEM_BYTES];
  int t = threadIdx.x;
  int w = t >> 6, l = t & 63;

  if (blockIdx.x < B_) {
    // ---------------- producer: FPS (8 waves, same math)
    float* xyz_s = (float*)smem;                                   // 49152 B
    int* idx_s = (int*)(smem + 49152);                             // 4096 B
    unsigned long long* keys_s = (unsigned long long*)(smem + 53248);  // 2*FPS_W
    int b = blockIdx.x;
    const float* xb = xyz + (size_t)b * N_ * 3;
    for (int i = t; i < N_ * 3; i += FPS_T) xyz_s[i] = xb[i];
    __syncthreads();
    float px[FPS_P], py[FPS_P], pz[FPS_P], dd[FPS_P];
#pragma unroll
    for (int j = 0; j < FPS_P; ++j) {
      int n = t + j * FPS_T;
      px[j] = xyz_s[n * 3 + 0];
      py[j] = xyz_s[n * 3 + 1];
      pz[j] = xyz_s[n * 3 + 2];
      dd[j] = 1e10f;
    }
    int fi = 0;
#pragma unroll 1
    for (int s = 0; s < S_; ++s) {
      if (t == 0) {
        idx_s[s] = fi;
        __hip_atomic_store(&pub[(b << 10) + s], fi + 1, __ATOMIC_RELAXED,
                           __HIP_MEMORY_SCOPE_AGENT);
      }
      float cx = xyz_s[fi * 3 + 0], cy = xyz_s[fi * 3 + 1], cz = xyz_s[fi * 3 + 2];
      float bv = -1.0f;
      int bi = 0;
#pragma unroll
      for (int j = 0; j < FPS_P; ++j) {
        float dx = __fsub_rn(px[j], cx);
        float dy = __fsub_rn(py[j], cy);
        float dz = __fsub_rn(pz[j], cz);
        float d = __fadd_rn(__fadd_rn(__fmul_rn(dx, dx), __fmul_rn(dy, dy)),
                            __fmul_rn(dz, dz));
        d = fminf(dd[j], d);
        dd[j] = d;
        if (d > bv) { bv = d; bi = t + j * FPS_T; }
      }
      unsigned hi = __float_as_uint(bv);
      unsigned lo = (unsigned)(N_ - 1 - bi);
      dpp_max_u64<0x111>(hi, lo);
      dpp_max_u64<0x112>(hi, lo);
      dpp_max_u64<0x114>(hi, lo);
      dpp_max_u64<0x118>(hi, lo);
      dpp_max_u64<0x142>(hi, lo);
      dpp_max_u64<0x143>(hi, lo);
      unsigned whi = (unsigned)__builtin_amdgcn_readlane((int)hi, 63);
      unsigned wlo = (unsigned)__builtin_amdgcn_readlane((int)lo, 63);
      if ((t & 63) == 0)
        keys_s[(s & 1) * FPS_W + (t >> 6)] =
            ((unsigned long long)whi << 32) | wlo;
      __syncthreads();
      unsigned long long m = keys_s[(s & 1) * FPS_W + 0];
#pragma unroll
      for (int ww = 1; ww < FPS_W; ++ww) {
        unsigned long long k = keys_s[(s & 1) * FPS_W + ww];
        m = k > m ? k : m;
      }
      fi = (N_ - 1) - (int)(unsigned)(m & 0xFFFFFFFFULL);
    }
    __syncthreads();
    for (int s = t; s < S_; s += FPS_T) {
      int i = idx_s[s];
      out_newxyz[((size_t)b * S_ + s) * 3 + 0] = xyz_s[i * 3 + 0];
      out_newxyz[((size_t)b * S_ + s) * 3 + 1] = xyz_s[i * 3 + 1];
      out_newxyz[((size_t)b * S_ + s) * 3 + 2] = xyz_s[i * 3 + 2];
    }
    return;
  }

  // ---------------- consumer: per-wave kNN + gemm0
  int n16 = l & 15, quad = l >> 4;
  U4S8 bf0[4][3];
  float b0v[4], ssum[4], ssq[4];
#pragma unroll
  for (int nt = 0; nt < 4; ++nt) {
#pragma unroll
    for (int kc = 0; kc < 3; ++kc)
      bf0[nt][kc].u = *reinterpret_cast<const uint4*>(
          wB0 + (size_t)(nt * 16 + n16) * 96 + kc * 32 + quad * 8);
    b0v[nt] = bias0[nt * 16 + n16];
    ssum[nt] = 0.0f;
    ssq[nt] = 0.0f;
  }
  float* ltw = (float*)(smem + w * (16 * 68 * 4));  // per-wave 4352 B bounce
  int wid = (blockIdx.x - B_) * 8 + w;              // 0..1919

#pragma unroll 1
  for (int r = wid; r < B_ * S_; r += NCONS_W) {
    int b = r & 15, s = r >> 4;
    int bs = (b << 10) + s;
    int pv = 0;
    if (l == 0) {
      int tries = 0;
      while ((pv = __hip_atomic_load(&pub[bs], __ATOMIC_RELAXED,
                                     __HIP_MEMORY_SCOPE_AGENT)) == 0) {
        __builtin_amdgcn_s_sleep(32);
        if (++tries > 65536) break;  // visible-failure valve, never trips normally
      }
    }
    pv = __shfl(pv, 0);
    int ci = pv - 1;
    if (ci < 0) ci = 0;  // valve tripped -> wrong-but-safe
    const float* xb = xyz + (size_t)b * N_ * 3;
    const float* pnb = ptn + (size_t)b * N_;
    float sx = xb[ci * 3 + 0], sy = xb[ci * 3 + 1], sz = xb[ci * 3 + 2];
    float nxn = pnb[ci];

    // ---- kNN distances (identical math) ----
    unsigned u[64];
#pragma unroll
    for (int j = 0; j < 64; ++j) {
      int nn = j * 64 + l;
      float x = xb[nn * 3 + 0], y = xb[nn * 3 + 1], z = xb[nn * 3 + 2];
      float e = __fadd_rn(__fadd_rn(__fmul_rn(sx, x), __fmul_rn(sy, y)),
                          __fmul_rn(sz, z));
      float d = __fadd_rn(__fadd_rn(nxn, pnb[nn]), __fmul_rn(-2.0f, e));
      int sb = __float_as_int(d);
      u[j] = (sb < 0) ? ~((unsigned)sb) : (((unsigned)sb) | 0x80000000u);
    }
    // ---- top-K selection: grouped tournament + DPP u64 min-reduce ----
    unsigned keep = 0;
#pragma unroll 1
    for (int p = 0; p < K_; ++p) {
      // per-lane argmin over u[0..63], lowest j wins ties (strict <, left-kept)
      unsigned gv[8], gj_[8];
#pragma unroll
      for (int g = 0; g < 8; ++g) {
        unsigned bv = u[g * 8];
        unsigned bj = (unsigned)(g * 8);
#pragma unroll
        for (int j2 = 1; j2 < 8; ++j2) {
          unsigned uu = u[g * 8 + j2];
          bool tk = uu < bv;
          bv = tk ? uu : bv;
          bj = tk ? (unsigned)(g * 8 + j2) : bj;
        }
        gv[g] = bv;
        gj_[g] = bj;
      }
#pragma unroll
      for (int st = 4; st >= 1; st >>= 1)
#pragma unroll
        for (int i2 = 0; i2 < 4; ++i2) {
          if (i2 < st) {
            bool tk = gv[i2 + st] < gv[i2];  // tie -> keep left (lower j)
            gv[i2] = tk ? gv[i2 + st] : gv[i2];
            gj_[i2] = tk ? gj_[i2 + st] : gj_[i2];
          }
        }
      // wave min on (value, global-idx): max-reduce of inverted keys via DPP
      unsigned hi = ~gv[0];
      unsigned lo = ~(gj_[0] * 64u + (unsigned)l);
      dpp_max_u64<0x111>(hi, lo);
      dpp_max_u64<0x112>(hi, lo);
      dpp_max_u64<0x114>(hi, lo);
      dpp_max_u64<0x118>(hi, lo);
      dpp_max_u64<0x142>(hi, lo);
      dpp_max_u64<0x143>(hi, lo);
      unsigned wlo = (unsigned)__builtin_amdgcn_readlane((int)lo, 63);
      unsigned gn = ~wlo;  // global index of winner (min value, then min idx)
      if (l == p) keep = gn;
      if ((gn & 63u) == (unsigned)l) {
        int gj = (int)(gn >> 6);
#pragma unroll
        for (int j = 0; j < 64; ++j)
          if (j == gj) u[j] = 0xFFFFFFFFu;
      }
    }

    // ---- gemm0: two 16-row MFMA tiles for this sample ----
#pragma unroll 1
    for (int t2 = 0; t2 < 2; ++t2) {
      int rb = bs * 32 + t2 * 16;
      int idxr = __shfl((int)keep, t2 * 16 + n16);
      const float* pbase = points + (size_t)b * N_ * 64 + (size_t)idxr * 64;
      U4S8 af[3];
#pragma unroll
      for (int kc = 0; kc < 2; ++kc) {
        float4 va = *reinterpret_cast<const float4*>(pbase + kc * 32 + quad * 8);
        float4 vb = *reinterpret_cast<const float4*>(pbase + kc * 32 + quad * 8 + 4);
        af[kc].u = make_uint4(pkrne(va.x, va.y), pkrne(va.z, va.w),
                              pkrne(vb.x, vb.y), pkrne(vb.z, vb.w));
      }
      if (quad == 0) {
        const float* xb3 = xb + (size_t)idxr * 3;
        float dx = __fsub_rn(xb3[0], sx);
        float dy = __fsub_rn(xb3[1], sy);
        float dz = __fsub_rn(xb3[2], sz);
        af[2].u = make_uint4(pkrne(dx, dy), (unsigned)f2bf(dz), 0u, 0u);
      } else {
        af[2].u = make_uint4(0u, 0u, 0u, 0u);
      }
      floatx4 acc[4];
#pragma unroll
      for (int nt = 0; nt < 4; ++nt) acc[nt] = floatx4{0.f, 0.f, 0.f, 0.f};
#pragma unroll
      for (int kc = 0; kc < 3; ++kc)
#pragma unroll
        for (int nt = 0; nt < 4; ++nt)
          acc[nt] = __builtin_amdgcn_mfma_f32_16x16x32_bf16(
              af[kc].v, bf0[nt][kc].v, acc[nt], 0, 0, 0);
#pragma unroll
      for (int nt = 0; nt < 4; ++nt)
#pragma unroll
        for (int rI = 0; rI < 4; ++rI) {
          float ys = acc[nt][rI] + b0v[nt];
          ssum[nt] += ys;
          ssq[nt] = fmaf(ys, ys, ssq[nt]);
          ltw[(quad * 4 + rI) * 68 + nt * 16 + n16] = ys;
        }
      const float* lrow = ltw + n16 * 68 + quad * 16;
      float4 va = *reinterpret_cast<const float4*>(lrow);
      float4 vb = *reinterpret_cast<const float4*>(lrow + 4);
      float4 vc = *reinterpret_cast<const float4*>(lrow + 8);
      float4 vd = *reinterpret_cast<const float4*>(lrow + 12);
      ushort_t* yo = y0 + (size_t)(rb + n16) * 64 + quad * 16;
      *reinterpret_cast<uint4*>(yo) =
          make_uint4(pkhu(va.x, va.y), pkhu(va.z, va.w), pkhu(vb.x, vb.y), pkhu(vb.z, vb.w));
      *reinterpret_cast<uint4*>(yo + 8) =
          make_uint4(pkhu(vc.x, vc.y), pkhu(vc.z, vc.w), pkhu(vd.x, vd.y), pkhu(vd.z, vd.w));
    }
  }

  // ---- stats flush (once per wave) ----
  float* stp = stats + (size_t)(wid & (NSLOT - 1)) * 64 * 2;
#pragma unroll
  for (int nt = 0; nt < 4; ++nt) {
    float s = ssum[nt], q = ssq[nt];
    s += __shfl_down(s, 16); q += __shfl_down(q, 16);
    s += __shfl_down(s, 32); q += __shfl_down(q, 32);
    if (l < 16) {
      atomicAdd(&stp[(size_t)(nt * 16 + l) * 2 + 0], s);
      atomicAdd(&stp[(size_t)(nt * 16 + l) * 2 + 1], q);
    }
  }
}

// ================================================================ gemm1 (MFMA)
__global__ __launch_bounds__(256) void gemm1_mfma(
    const ushort_t* __restrict__ y0, const float* __restrict__ bnp,
    const ushort_t* __restrict__ wB1, const float* __restrict__ bias1,
    ushort_t* __restrict__ y1, float* __restrict__ stats) {
  __shared__ __align__(16) float lt[4][16 * 68];
  int t = threadIdx.x;
  int w = t >> 6, l = t & 63;
  int n = l & 15, quad = l >> 4;
  U4S8 bf[4][2];
#pragma unroll
  for (int nt = 0; nt < 4; ++nt)
#pragma unroll
    for (int kc = 0; kc < 2; ++kc)
      bf[nt][kc].u = *reinterpret_cast<const uint4*>(
          wB1 + (size_t)(nt * 16 + n) * 64 + kc * 32 + quad * 8);
  float4 scA[2], scB[2], shA[2], shB[2];
#pragma unroll
  for (int kc = 0; kc < 2; ++kc) {
    int cb = kc * 32 + quad * 8;
    scA[kc] = *reinterpret_cast<const float4*>(&bnp[cb]);
    scB[kc] = *reinterpret_cast<const float4*>(&bnp[cb + 4]);
    shA[kc] = *reinterpret_cast<const float4*>(&bnp[64 + cb]);
    shB[kc] = *reinterpret_cast<const float4*>(&bnp[64 + cb + 4]);
  }
  float b1v[4], ssum[4], ssq[4];
#pragma unroll
  for (int nt = 0; nt < 4; ++nt) {
    b1v[nt] = bias1[nt * 16 + n];
    ssum[nt] = 0.0f;
    ssq[nt] = 0.0f;
  }
  int rowbase0 = blockIdx.x * 1024 + w * 256;
  float* ltw = lt[w];
#pragma unroll 1
  for (int tile = 0; tile < 16; ++tile) {
    int rb = rowbase0 + tile * 16;
    U4S8 af[2];
#pragma unroll
    for (int kc = 0; kc < 2; ++kc) {
      uint4 xv = *reinterpret_cast<const uint4*>(
          y0 + (size_t)(rb + n) * 64 + kc * 32 + quad * 8);
      af[kc].u = bn_relu_pack(xv, scA[kc], scB[kc], shA[kc], shB[kc]);
    }
    floatx4 acc[4];
#pragma unroll
    for (int nt = 0; nt < 4; ++nt) acc[nt] = floatx4{0.f, 0.f, 0.f, 0.f};
#pragma unroll
    for (int kc = 0; kc < 2; ++kc)
#pragma unroll
      for (int nt = 0; nt < 4; ++nt)
        acc[nt] = __builtin_amdgcn_mfma_f32_16x16x32_bf16(
            af[kc].v, bf[nt][kc].v, acc[nt], 0, 0, 0);
#pragma unroll
    for (int nt = 0; nt < 4; ++nt)
#pragma unroll
      for (int rI = 0; rI < 4; ++rI) {
        float ys = acc[nt][rI] + b1v[nt];
        ssum[nt] += ys;
        ssq[nt] = fmaf(ys, ys, ssq[nt]);
        ltw[(quad * 4 + rI) * 68 + nt * 16 + n] = ys;
      }
    const float* lrow = ltw + n * 68 + quad * 16;
    float4 va = *reinterpret_cast<const float4*>(lrow);
    float4 vb = *reinterpret_cast<const float4*>(lrow + 4);
    float4 vc = *reinterpret_cast<const float4*>(lrow + 8);
    float4 vd = *reinterpret_cast<const float4*>(lrow + 12);
    ushort_t* yo = y1 + (size_t)(rb + n) * 64 + quad * 16;
    *reinterpret_cast<uint4*>(yo) =
        make_uint4(pkhu(va.x, va.y), pkhu(va.z, va.w), pkhu(vb.x, vb.y), pkhu(vb.z, vb.w));
    *reinterpret_cast<uint4*>(yo + 8) =
        make_uint4(pkhu(vc.x, vc.y), pkhu(vc.z, vc.w), pkhu(vd.x, vd.y), pkhu(vd.z, vd.w));
  }
  float* stp = stats + (size_t)((blockIdx.x * 4 + w) & (NSLOT - 1)) * 64 * 2;
#pragma unroll
  for (int nt = 0; nt < 4; ++nt) {
    float s = ssum[nt], q = ssq[nt];
    s += __shfl_down(s, 16); q += __shfl_down(q, 16);
    s += __shfl_down(s, 32); q += __shfl_down(q, 32);
    if (l < 16) {
      atomicAdd(&stp[(size_t)(nt * 16 + l) * 2 + 0], s);
      atomicAdd(&stp[(size_t)(nt * 16 + l) * 2 + 1], q);
    }
  }
}

// ================================================================ gemm2 (MFMA)
__global__ __launch_bounds__(256) void gemm2_mfma(
    const ushort_t* __restrict__ y1, const float* __restrict__ bnp,
    const ushort_t* __restrict__ wB2, const float* __restrict__ bias2,
    float* __restrict__ stats, float* __restrict__ maxY, float* __restrict__ minY) {
  int t = threadIdx.x;
  int w = t >> 6, l = t & 63;
  int n = l & 15, quad = l >> 4;
  U4S8 bf[8][2];
#pragma unroll
  for (int nt = 0; nt < 8; ++nt)
#pragma unroll
    for (int kc = 0; kc < 2; ++kc)
      bf[nt][kc].u = *reinterpret_cast<const uint4*>(
          wB2 + (size_t)(nt * 16 + n) * 64 + kc * 32 + quad * 8);
  float4 scA[2], scB[2], shA[2], shB[2];
#pragma unroll
  for (int kc = 0; kc < 2; ++kc) {
    int cb = kc * 32 + quad * 8;
    scA[kc] = *reinterpret_cast<const float4*>(&bnp[128 + cb]);
    scB[kc] = *reinterpret_cast<const float4*>(&bnp[128 + cb + 4]);
    shA[kc] = *reinterpret_cast<const float4*>(&bnp[192 + cb]);
    shB[kc] = *reinterpret_cast<const float4*>(&bnp[192 + cb + 4]);
  }
  float b2v[8], ssum[8], ssq[8], mxv[8], mnv[8];
#pragma unroll
  for (int nt = 0; nt < 8; ++nt) {
    b2v[nt] = bias2[nt * 16 + n];
    ssum[nt] = 0.0f;
    ssq[nt] = 0.0f;
    mxv[nt] = -3.4e38f;
    mnv[nt] = 3.4e38f;
  }
  int rowbase0 = blockIdx.x * 1024 + w * 256;
#pragma unroll 1
  for (int tile = 0; tile < 16; ++tile) {
    int rb = rowbase0 + tile * 16;
    U4S8 af[2];
#pragma unroll
    for (int kc = 0; kc < 2; ++kc) {
      uint4 xv = *reinterpret_cast<const uint4*>(
          y1 + (size_t)(rb + n) * 64 + kc * 32 + quad * 8);
      af[kc].u = bn_relu_pack(xv, scA[kc], scB[kc], shA[kc], shB[kc]);
    }
    floatx4 acc[8];
#pragma unroll
    for (int nt = 0; nt < 8; ++nt) acc[nt] = floatx4{0.f, 0.f, 0.f, 0.f};
#pragma unroll
    for (int kc = 0; kc < 2; ++kc)
#pragma unroll
      for (int nt = 0; nt < 8; ++nt)
        acc[nt] = __builtin_amdgcn_mfma_f32_16x16x32_bf16(
            af[kc].v, bf[nt][kc].v, acc[nt], 0, 0, 0);
#pragma unroll
    for (int nt = 0; nt < 8; ++nt)
#pragma unroll
      for (int rI = 0; rI < 4; ++rI) {
        float ya = acc[nt][rI] + b2v[nt];
        ssum[nt] += ya;
        ssq[nt] = fmaf(ya, ya, ssq[nt]);
        mxv[nt] = fmaxf(mxv[nt], ya);
        mnv[nt] = fminf(mnv[nt], ya);
      }
    if (tile & 1) {
      int sidx = (rowbase0 >> 5) + (tile >> 1);
#pragma unroll
      for (int nt = 0; nt < 8; ++nt) {
        float mx = mxv[nt], mn = mnv[nt];
        mx = fmaxf(mx, __shfl_down(mx, 16));
        mn = fminf(mn, __shfl_down(mn, 16));
        mx = fmaxf(mx, __shfl_down(mx, 32));
        mn = fminf(mn, __shfl_down(mn, 32));
        if (l < 16) {
          maxY[(size_t)sidx * 128 + nt * 16 + l] = mx;
          minY[(size_t)sidx * 128 + nt * 16 + l] = mn;
        }
        mxv[nt] = -3.4e38f;
        mnv[nt] = 3.4e38f;
      }
    }
  }
  float* stp = stats + (size_t)((blockIdx.x * 4 + w) & (NSLOT - 1)) * 128 * 2;
#pragma unroll
  for (int nt = 0; nt < 8; ++nt) {
    float s = ssum[nt], q = ssq[nt];
    s += __shfl_down(s, 16); q += __shfl_down(q, 16);
    s += __shfl_down(s, 32); q += __shfl_down(q, 32);
    if (l < 16) {
      atomicAdd(&stp[(size_t)(nt * 16 + l) * 2 + 0], s);
      atomicAdd(&stp[(size_t)(nt * 16 + l) * 2 + 1], q);
    }
  }
}

// ---------------------------------------------------------------- BN finalize
__global__ void bn_finalize(const float* __restrict__ st, int cout,
                            const float* __restrict__ gamma,
                            const float* __restrict__ beta,
                            float* __restrict__ scale, float* __restrict__ shift) {
  int o = threadIdx.x;
  if (o >= cout) return;
  float s = 0.0f, q = 0.0f;
  for (int i = 0; i < NSLOT; ++i) {
    s += st[((size_t)i * cout + o) * 2 + 0];
    q += st[((size_t)i * cout + o) * 2 + 1];
  }
  float mean = s * (1.0f / CNT_F);
  float var = q * (1.0f / CNT_F) - mean * mean;
  float sc = gamma[o] / sqrtf(var + 1e-5f);
  scale[o] = sc;
  shift[o] = beta[o] - mean * sc;
}

// ---------------------------------------------------------------- pooling
__global__ __launch_bounds__(256) void pool_kernel(
    const float* __restrict__ maxY, const float* __restrict__ minY,
    const float* __restrict__ bnp, float* __restrict__ out) {
  __shared__ float tile[128 * 65];
  int b = blockIdx.x >> 4;
  int sbase = (blockIdx.x & 15) * 64;
  int t = threadIdx.x;
#pragma unroll 4
  for (int i = 0; i < 32; ++i) {
    int e = i * 256 + t;
    int sl = e >> 7, o = e & 127;
    float sc = bnp[256 + o], sh = bnp[384 + o];
    size_t g = ((size_t)(b * S_ + sbase + sl)) * 128 + o;
    float v = (sc >= 0.0f) ? maxY[g] : minY[g];
    tile[o * 65 + sl] = fmaxf(fmaf(v, sc, sh), 0.0f);
  }
  __syncthreads();
  int sl = t & 63;
  for (int o2 = t >> 6; o2 < 128; o2 += 4) {
    out[((size_t)(b * 128 + o2)) * S_ + sbase + sl] = tile[o2 * 65 + sl];
  }
}

// ---------------------------------------------------------------- launch
static inline size_t alup(size_t x) { return (x + 255) & ~(size_t)255; }

extern "C" void kernel_launch(void* const* d_in, const int* in_sizes, int n_in,
                              void* d_out, int out_size, void* d_ws, size_t ws_size,
                              hipStream_t stream) {
  (void)in_sizes; (void)n_in; (void)out_size;
  const float* xyz = (const float*)d_in[0];
  const float* points = (const float*)d_in[1];
  const float* w0 = (const float*)d_in[2];
  const float* b0 = (const float*)d_in[3];
  const float* g0 = (const float*)d_in[4];
  const float* be0 = (const float*)d_in[5];
  const float* w1 = (const float*)d_in[6];
  const float* b1 = (const float*)d_in[7];
  const float* g1 = (const float*)d_in[8];
  const float* be1 = (const float*)d_in[9];
  const float* w2 = (const float*)d_in[10];
  const float* b2 = (const float*)d_in[11];
  const float* g2 = (const float*)d_in[12];
  const float* be2 = (const float*)d_in[13];
  float* out_newxyz = (float*)d_out;
  float* out_newpts = out_newxyz + (size_t)B_ * S_ * 3;

  char* p = (char*)d_ws;
  int* pub = (int*)p;     p += alup((size_t)B_ * S_ * 4);
  float* ptn = (float*)p; p += alup((size_t)B_ * N_ * 4);
  float* st0 = (float*)p; p += (size_t)NSLOT * 64 * 2 * 4;
  float* st1 = (float*)p; p += (size_t)NSLOT * 64 * 2 * 4;
  float* st2 = (float*)p; p += (size_t)NSLOT * 128 * 2 * 4;
  float* bnp = (float*)p; p += alup(512 * 4);
  ushort_t* wB0 = (ushort_t*)p; p += alup(64 * 96 * 2);
  ushort_t* wB1 = (ushort_t*)p; p += alup(64 * 64 * 2);
  ushort_t* wB2 = (ushort_t*)p; p += alup(128 * 64 * 2);
  float* maxY = (float*)p; p += (size_t)B_ * S_ * 128 * 4;
  float* minY = (float*)p; p += (size_t)B_ * S_ * 128 * 4;
  ushort_t* y0 = (ushort_t*)p; p += (size_t)RWS * 64 * 2;
  ushort_t* y1 = (ushort_t*)p; p += (size_t)RWS * 64 * 2;
  if ((size_t)(p - (char*)d_ws) > ws_size) return;  // visible failure

  float* sc0 = bnp;       float* sh0 = bnp + 64;
  float* sc1 = bnp + 128; float* sh1 = bnp + 192;
  float* sc2 = bnp + 256; float* sh2 = bnp + 384;

  hipMemsetAsync(st0, 0, (size_t)NSLOT * (64 + 64 + 128) * 2 * 4, stream);
  hipMemsetAsync(pub, 0, (size_t)B_ * S_ * 4, stream);
  prep_all<<<256, 256, 0, stream>>>(xyz, ptn, w0, w1, w2, wB0, wB1, wB2);
  fused_kernel<<<256, 512, 0, stream>>>(
      xyz, points, ptn, wB0, b0, pub, out_newxyz, y0, st0);
  bn_finalize<<<1, 128, 0, stream>>>(st0, 64, g0, be0, sc0, sh0);
  gemm1_mfma<<<RWS / 1024, 256, 0, stream>>>(y0, bnp, wB1, b1, y1, st1);
  bn_finalize<<<1, 128, 0, stream>>>(st1, 64, g1, be1, sc1, sh1);
  gemm2_mfma<<<RWS / 1024, 256, 0, stream>>>(y1, bnp, wB2, b2, st2, maxY, minY);
  bn_finalize<<<1, 128, 0, stream>>>(st2, 128, g2, be2, sc2, sh2);
  pool_kernel<<<B_ * (S_ / 64), 256, 0, stream>>>(maxY, minY, bnp, out_newpts);
}

// Round 4
// 910.328 us; speedup vs baseline: 1.3952x; 1.0937x over previous
//
#include <hip/hip_runtime.h>

#define B_ 16
#define N_ 4096
#define S_ 1024
#define K_ 32
#define NSLOT 128
#define CNT_F 524288.0f   // B*S*K
#define RWS 524288        // total rows = B*S*K

typedef unsigned short ushort_t;
typedef short short8 __attribute__((ext_vector_type(8)));
typedef float floatx4 __attribute__((ext_vector_type(4)));
union U4S8 { uint4 u; short8 v; };

__device__ __forceinline__ ushort_t f2bf(float f) {  // RNE
  unsigned u = __float_as_uint(f);
  unsigned r = (u + 0x7fffu + ((u >> 16) & 1u)) >> 16;
  return (ushort_t)r;
}
__device__ __forceinline__ unsigned pkrne(float a, float b) {
  return (unsigned)f2bf(a) | ((unsigned)f2bf(b) << 16);
}
__device__ __forceinline__ unsigned pkhu(float a, float b) {  // half-up pair
  return ((__float_as_uint(a) + 0x8000u) >> 16) |
         ((__float_as_uint(b) + 0x8000u) & 0xffff0000u);
}

// unpack 8 bf16, apply bn scale/shift + relu, repack as bf16 (half-up)
__device__ __forceinline__ uint4 bn_relu_pack(uint4 xv, float4 sca, float4 scb,
                                              float4 sha, float4 shb) {
  float x0 = __uint_as_float(xv.x << 16);
  float x1 = __uint_as_float(xv.x & 0xffff0000u);
  float x2 = __uint_as_float(xv.y << 16);
  float x3 = __uint_as_float(xv.y & 0xffff0000u);
  float x4 = __uint_as_float(xv.z << 16);
  float x5 = __uint_as_float(xv.z & 0xffff0000u);
  float x6 = __uint_as_float(xv.w << 16);
  float x7 = __uint_as_float(xv.w & 0xffff0000u);
  x0 = fmaxf(fmaf(x0, sca.x, sha.x), 0.0f);
  x1 = fmaxf(fmaf(x1, sca.y, sha.y), 0.0f);
  x2 = fmaxf(fmaf(x2, sca.z, sha.z), 0.0f);
  x3 = fmaxf(fmaf(x3, sca.w, sha.w), 0.0f);
  x4 = fmaxf(fmaf(x4, scb.x, shb.x), 0.0f);
  x5 = fmaxf(fmaf(x5, scb.y, shb.y), 0.0f);
  x6 = fmaxf(fmaf(x6, scb.z, shb.z), 0.0f);
  x7 = fmaxf(fmaf(x7, scb.w, shb.w), 0.0f);
  return make_uint4(pkhu(x0, x1), pkhu(x2, x3), pkhu(x4, x5), pkhu(x6, x7));
}

// ---------------------------------------------------------------- FPS params
#define FPS_T 256
#define FPS_P (N_ / FPS_T)   // 16
#define FPS_W (FPS_T / 64)   // 4

template <int CTRL>
__device__ __forceinline__ void dpp_max_u64(unsigned& hi, unsigned& lo) {
  unsigned h2 = (unsigned)__builtin_amdgcn_update_dpp(0, (int)hi, CTRL, 0xf, 0xf, true);
  unsigned l2 = (unsigned)__builtin_amdgcn_update_dpp(0, (int)lo, CTRL, 0xf, 0xf, true);
  bool take = (h2 > hi) || (h2 == hi && l2 > lo);
  hi = take ? h2 : hi;
  lo = take ? l2 : lo;
}

// ---------------------------------------------------------------- prep (ptnorm + weights)
__global__ __launch_bounds__(256) void prep_all(
    const float* __restrict__ xyz, float* __restrict__ pt,
    const float* __restrict__ w0, const float* __restrict__ w1,
    const float* __restrict__ w2, ushort_t* __restrict__ wB0,
    ushort_t* __restrict__ wB1, ushort_t* __restrict__ wB2) {
  int i = blockIdx.x * 256 + threadIdx.x;  // < 65536 = B*N
  float x = xyz[(size_t)i * 3 + 0];
  float y = xyz[(size_t)i * 3 + 1];
  float z = xyz[(size_t)i * 3 + 2];
  pt[i] = __fadd_rn(__fadd_rn(__fmul_rn(x, x), __fmul_rn(y, y)), __fmul_rn(z, z));
  // wB0: [o][96] = [p-weights(64), xyz-weights(3), zeros(29)]
  if (i < 64 * 96) {
    int o = i / 96, c = i % 96;
    ushort_t v = 0;
    if (c < 64) v = f2bf(w0[o * 67 + 3 + c]);
    else if (c < 67) v = f2bf(w0[o * 67 + (c - 64)]);
    wB0[i] = v;
  }
  if (i < 64 * 64) wB1[i] = f2bf(w1[i]);
  if (i < 128 * 64) wB2[i] = f2bf(w2[i]);
}

// ================================================================ fused
// Grid 512 x 256 threads, LDS padded to 55 KiB -> exactly 2 blocks/CU
// (3x55K > 160K), VGPR capped at 256 via launch_bounds(256,2) (232 measured
// in the identical R1 consumer codegen -> no spill). 512 blocks = 2/CU x
// 256 CU: ALL blocks co-resident regardless of dispatch order => deadlock-
// free producer/consumer handshake.
// Blocks 0..15: FPS producer (one per batch), s_setprio(3) so the serial
// FPS chain wins SIMD issue arbitration vs its co-resident consumer block.
// Blocks 16..511: consumer blocks, 4 waves each (1984 waves, 2 waves/SIMD);
// per sample: spin for published index, kNN (register-resident u[64],
// grouped-tournament argmin + DPP u64 reduce), then two 16-row gemm0 MFMA
// tiles (neighbor indices handed over via __shfl).
#define SMEM_BYTES 56320
#define NBLK 512
#define NCONS_W ((NBLK - B_) * 4)  // 1984 consumer waves

__global__ __launch_bounds__(256, 2) void fused_kernel(
    const float* __restrict__ xyz, const float* __restrict__ points,
    const float* __restrict__ ptn, const ushort_t* __restrict__ wB0,
    const float* __restrict__ bias0, int* __restrict__ pub,
    float* __restrict__ out_newxyz, ushort_t* __restrict__ y0,
    float* __restrict__ stats) {
  __shared__ __align__(16) char smem[SMEM_BYTES];
  int t = threadIdx.x;
  int w = t >> 6, l = t & 63;

  if (blockIdx.x < B_) {
    // ---------------- producer: FPS (identical math to R0 fps_kernel)
    float* xyz_s = (float*)smem;                                   // 49152 B
    int* idx_s = (int*)(smem + 49152);                             // 4096 B
    unsigned long long* keys_s = (unsigned long long*)(smem + 53248);  // 2*FPS_W
    int b = blockIdx.x;
    const float* xb = xyz + (size_t)b * N_ * 3;
    for (int i = t; i < N_ * 3; i += FPS_T) xyz_s[i] = xb[i];
    __syncthreads();
    float px[FPS_P], py[FPS_P], pz[FPS_P], dd[FPS_P];
#pragma unroll
    for (int j = 0; j < FPS_P; ++j) {
      int n = t + j * FPS_T;
      px[j] = xyz_s[n * 3 + 0];
      py[j] = xyz_s[n * 3 + 1];
      pz[j] = xyz_s[n * 3 + 2];
      dd[j] = 1e10f;
    }
    __builtin_amdgcn_s_setprio(3);  // beat co-resident consumer block
    int fi = 0;
#pragma unroll 1
    for (int s = 0; s < S_; ++s) {
      if (t == 0) {
        idx_s[s] = fi;
        __hip_atomic_store(&pub[(b << 10) + s], fi + 1, __ATOMIC_RELAXED,
                           __HIP_MEMORY_SCOPE_AGENT);
      }
      float cx = xyz_s[fi * 3 + 0], cy = xyz_s[fi * 3 + 1], cz = xyz_s[fi * 3 + 2];
      float bv = -1.0f;
      int bi = 0;
#pragma unroll
      for (int j = 0; j < FPS_P; ++j) {
        float dx = __fsub_rn(px[j], cx);
        float dy = __fsub_rn(py[j], cy);
        float dz = __fsub_rn(pz[j], cz);
        float d = __fadd_rn(__fadd_rn(__fmul_rn(dx, dx), __fmul_rn(dy, dy)),
                            __fmul_rn(dz, dz));
        d = fminf(dd[j], d);
        dd[j] = d;
        if (d > bv) { bv = d; bi = t + j * FPS_T; }
      }
      unsigned hi = __float_as_uint(bv);
      unsigned lo = (unsigned)(N_ - 1 - bi);
      dpp_max_u64<0x111>(hi, lo);
      dpp_max_u64<0x112>(hi, lo);
      dpp_max_u64<0x114>(hi, lo);
      dpp_max_u64<0x118>(hi, lo);
      dpp_max_u64<0x142>(hi, lo);
      dpp_max_u64<0x143>(hi, lo);
      unsigned whi = (unsigned)__builtin_amdgcn_readlane((int)hi, 63);
      unsigned wlo = (unsigned)__builtin_amdgcn_readlane((int)lo, 63);
      if ((t & 63) == 0)
        keys_s[(s & 1) * FPS_W + (t >> 6)] =
            ((unsigned long long)whi << 32) | wlo;
      __syncthreads();
      unsigned long long m = keys_s[(s & 1) * FPS_W + 0];
#pragma unroll
      for (int ww = 1; ww < FPS_W; ++ww) {
        unsigned long long k = keys_s[(s & 1) * FPS_W + ww];
        m = k > m ? k : m;
      }
      fi = (N_ - 1) - (int)(unsigned)(m & 0xFFFFFFFFULL);
    }
    __builtin_amdgcn_s_setprio(0);
    __syncthreads();
    for (int s = t; s < S_; s += FPS_T) {
      int i = idx_s[s];
      out_newxyz[((size_t)b * S_ + s) * 3 + 0] = xyz_s[i * 3 + 0];
      out_newxyz[((size_t)b * S_ + s) * 3 + 1] = xyz_s[i * 3 + 1];
      out_newxyz[((size_t)b * S_ + s) * 3 + 2] = xyz_s[i * 3 + 2];
    }
    return;
  }

  // ---------------- consumer: per-wave kNN + gemm0
  int n16 = l & 15, quad = l >> 4;
  U4S8 bf0[4][3];
  float b0v[4], ssum[4], ssq[4];
#pragma unroll
  for (int nt = 0; nt < 4; ++nt) {
#pragma unroll
    for (int kc = 0; kc < 3; ++kc)
      bf0[nt][kc].u = *reinterpret_cast<const uint4*>(
          wB0 + (size_t)(nt * 16 + n16) * 96 + kc * 32 + quad * 8);
    b0v[nt] = bias0[nt * 16 + n16];
    ssum[nt] = 0.0f;
    ssq[nt] = 0.0f;
  }
  float* ltw = (float*)(smem + w * (16 * 68 * 4));  // per-wave 4352 B bounce
  int wid = (blockIdx.x - B_) * 4 + w;              // 0..1983

#pragma unroll 1
  for (int r = wid; r < B_ * S_; r += NCONS_W) {
    int b = r & 15, s = r >> 4;
    int bs = (b << 10) + s;
    int pv = 0;
    if (l == 0) {
      int tries = 0;
      while ((pv = __hip_atomic_load(&pub[bs], __ATOMIC_RELAXED,
                                     __HIP_MEMORY_SCOPE_AGENT)) == 0) {
        __builtin_amdgcn_s_sleep(32);
        if (++tries > 65536) break;  // visible-failure valve, never trips normally
      }
    }
    pv = __shfl(pv, 0);
    int ci = pv - 1;
    if (ci < 0) ci = 0;  // valve tripped -> wrong-but-safe
    const float* xb = xyz + (size_t)b * N_ * 3;
    const float* pnb = ptn + (size_t)b * N_;
    float sx = xb[ci * 3 + 0], sy = xb[ci * 3 + 1], sz = xb[ci * 3 + 2];
    float nxn = pnb[ci];

    // ---- kNN distances (identical math) ----
    unsigned u[64];
#pragma unroll
    for (int j = 0; j < 64; ++j) {
      int nn = j * 64 + l;
      float x = xb[nn * 3 + 0], y = xb[nn * 3 + 1], z = xb[nn * 3 + 2];
      float e = __fadd_rn(__fadd_rn(__fmul_rn(sx, x), __fmul_rn(sy, y)),
                          __fmul_rn(sz, z));
      float d = __fadd_rn(__fadd_rn(nxn, pnb[nn]), __fmul_rn(-2.0f, e));
      int sb = __float_as_int(d);
      u[j] = (sb < 0) ? ~((unsigned)sb) : (((unsigned)sb) | 0x80000000u);
    }
    // ---- top-K selection: grouped tournament + DPP u64 min-reduce ----
    unsigned keep = 0;
#pragma unroll 1
    for (int p = 0; p < K_; ++p) {
      // per-lane argmin over u[0..63], lowest j wins ties (strict <, left-kept)
      unsigned gv[8], gj_[8];
#pragma unroll
      for (int g = 0; g < 8; ++g) {
        unsigned bv = u[g * 8];
        unsigned bj = (unsigned)(g * 8);
#pragma unroll
        for (int j2 = 1; j2 < 8; ++j2) {
          unsigned uu = u[g * 8 + j2];
          bool tk = uu < bv;
          bv = tk ? uu : bv;
          bj = tk ? (unsigned)(g * 8 + j2) : bj;
        }
        gv[g] = bv;
        gj_[g] = bj;
      }
#pragma unroll
      for (int st = 4; st >= 1; st >>= 1)
#pragma unroll
        for (int i2 = 0; i2 < 4; ++i2) {
          if (i2 < st) {
            bool tk = gv[i2 + st] < gv[i2];  // tie -> keep left (lower j)
            gv[i2] = tk ? gv[i2 + st] : gv[i2];
            gj_[i2] = tk ? gj_[i2 + st] : gj_[i2];
          }
        }
      // wave min on (value, global-idx): max-reduce of inverted keys via DPP
      unsigned hi = ~gv[0];
      unsigned lo = ~(gj_[0] * 64u + (unsigned)l);
      dpp_max_u64<0x111>(hi, lo);
      dpp_max_u64<0x112>(hi, lo);
      dpp_max_u64<0x114>(hi, lo);
      dpp_max_u64<0x118>(hi, lo);
      dpp_max_u64<0x142>(hi, lo);
      dpp_max_u64<0x143>(hi, lo);
      unsigned wlo = (unsigned)__builtin_amdgcn_readlane((int)lo, 63);
      unsigned gn = ~wlo;  // global index of winner (min value, then min idx)
      if (l == p) keep = gn;
      if ((gn & 63u) == (unsigned)l) {
        int gj = (int)(gn >> 6);
#pragma unroll
        for (int j = 0; j < 64; ++j)
          if (j == gj) u[j] = 0xFFFFFFFFu;
      }
    }

    // ---- gemm0: two 16-row MFMA tiles for this sample ----
#pragma unroll 1
    for (int t2 = 0; t2 < 2; ++t2) {
      int rb = bs * 32 + t2 * 16;
      int idxr = __shfl((int)keep, t2 * 16 + n16);
      const float* pbase = points + (size_t)b * N_ * 64 + (size_t)idxr * 64;
      U4S8 af[3];
#pragma unroll
      for (int kc = 0; kc < 2; ++kc) {
        float4 va = *reinterpret_cast<const float4*>(pbase + kc * 32 + quad * 8);
        float4 vb = *reinterpret_cast<const float4*>(pbase + kc * 32 + quad * 8 + 4);
        af[kc].u = make_uint4(pkrne(va.x, va.y), pkrne(va.z, va.w),
                              pkrne(vb.x, vb.y), pkrne(vb.z, vb.w));
      }
      if (quad == 0) {
        const float* xb3 = xb + (size_t)idxr * 3;
        float dx = __fsub_rn(xb3[0], sx);
        float dy = __fsub_rn(xb3[1], sy);
        float dz = __fsub_rn(xb3[2], sz);
        af[2].u = make_uint4(pkrne(dx, dy), (unsigned)f2bf(dz), 0u, 0u);
      } else {
        af[2].u = make_uint4(0u, 0u, 0u, 0u);
      }
      floatx4 acc[4];
#pragma unroll
      for (int nt = 0; nt < 4; ++nt) acc[nt] = floatx4{0.f, 0.f, 0.f, 0.f};
#pragma unroll
      for (int kc = 0; kc < 3; ++kc)
#pragma unroll
        for (int nt = 0; nt < 4; ++nt)
          acc[nt] = __builtin_amdgcn_mfma_f32_16x16x32_bf16(
              af[kc].v, bf0[nt][kc].v, acc[nt], 0, 0, 0);
#pragma unroll
      for (int nt = 0; nt < 4; ++nt)
#pragma unroll
        for (int rI = 0; rI < 4; ++rI) {
          float ys = acc[nt][rI] + b0v[nt];
          ssum[nt] += ys;
          ssq[nt] = fmaf(ys, ys, ssq[nt]);
          ltw[(quad * 4 + rI) * 68 + nt * 16 + n16] = ys;
        }
      const float* lrow = ltw + n16 * 68 + quad * 16;
      float4 va = *reinterpret_cast<const float4*>(lrow);
      float4 vb = *reinterpret_cast<const float4*>(lrow + 4);
      float4 vc = *reinterpret_cast<const float4*>(lrow + 8);
      float4 vd = *reinterpret_cast<const float4*>(lrow + 12);
      ushort_t* yo = y0 + (size_t)(rb + n16) * 64 + quad * 16;
      *reinterpret_cast<uint4*>(yo) =
          make_uint4(pkhu(va.x, va.y), pkhu(va.z, va.w), pkhu(vb.x, vb.y), pkhu(vb.z, vb.w));
      *reinterpret_cast<uint4*>(yo + 8) =
          make_uint4(pkhu(vc.x, vc.y), pkhu(vc.z, vc.w), pkhu(vd.x, vd.y), pkhu(vd.z, vd.w));
    }
  }

  // ---- stats flush (once per wave) ----
  float* stp = stats + (size_t)(wid & (NSLOT - 1)) * 64 * 2;
#pragma unroll
  for (int nt = 0; nt < 4; ++nt) {
    float s = ssum[nt], q = ssq[nt];
    s += __shfl_down(s, 16); q += __shfl_down(q, 16);
    s += __shfl_down(s, 32); q += __shfl_down(q, 32);
    if (l < 16) {
      atomicAdd(&stp[(size_t)(nt * 16 + l) * 2 + 0], s);
      atomicAdd(&stp[(size_t)(nt * 16 + l) * 2 + 1], q);
    }
  }
}

// ================================================================ gemm1 (MFMA)
__global__ __launch_bounds__(256) void gemm1_mfma(
    const ushort_t* __restrict__ y0, const float* __restrict__ bnp,
    const ushort_t* __restrict__ wB1, const float* __restrict__ bias1,
    ushort_t* __restrict__ y1, float* __restrict__ stats) {
  __shared__ __align__(16) float lt[4][16 * 68];
  int t = threadIdx.x;
  int w = t >> 6, l = t & 63;
  int n = l & 15, quad = l >> 4;
  U4S8 bf[4][2];
#pragma unroll
  for (int nt = 0; nt < 4; ++nt)
#pragma unroll
    for (int kc = 0; kc < 2; ++kc)
      bf[nt][kc].u = *reinterpret_cast<const uint4*>(
          wB1 + (size_t)(nt * 16 + n) * 64 + kc * 32 + quad * 8);
  float4 scA[2], scB[2], shA[2], shB[2];
#pragma unroll
  for (int kc = 0; kc < 2; ++kc) {
    int cb = kc * 32 + quad * 8;
    scA[kc] = *reinterpret_cast<const float4*>(&bnp[cb]);
    scB[kc] = *reinterpret_cast<const float4*>(&bnp[cb + 4]);
    shA[kc] = *reinterpret_cast<const float4*>(&bnp[64 + cb]);
    shB[kc] = *reinterpret_cast<const float4*>(&bnp[64 + cb + 4]);
  }
  float b1v[4], ssum[4], ssq[4];
#pragma unroll
  for (int nt = 0; nt < 4; ++nt) {
    b1v[nt] = bias1[nt * 16 + n];
    ssum[nt] = 0.0f;
    ssq[nt] = 0.0f;
  }
  int rowbase0 = blockIdx.x * 1024 + w * 256;
  float* ltw = lt[w];
#pragma unroll 1
  for (int tile = 0; tile < 16; ++tile) {
    int rb = rowbase0 + tile * 16;
    U4S8 af[2];
#pragma unroll
    for (int kc = 0; kc < 2; ++kc) {
      uint4 xv = *reinterpret_cast<const uint4*>(
          y0 + (size_t)(rb + n) * 64 + kc * 32 + quad * 8);
      af[kc].u = bn_relu_pack(xv, scA[kc], scB[kc], shA[kc], shB[kc]);
    }
    floatx4 acc[4];
#pragma unroll
    for (int nt = 0; nt < 4; ++nt) acc[nt] = floatx4{0.f, 0.f, 0.f, 0.f};
#pragma unroll
    for (int kc = 0; kc < 2; ++kc)
#pragma unroll
      for (int nt = 0; nt < 4; ++nt)
        acc[nt] = __builtin_amdgcn_mfma_f32_16x16x32_bf16(
            af[kc].v, bf[nt][kc].v, acc[nt], 0, 0, 0);
#pragma unroll
    for (int nt = 0; nt < 4; ++nt)
#pragma unroll
      for (int rI = 0; rI < 4; ++rI) {
        float ys = acc[nt][rI] + b1v[nt];
        ssum[nt] += ys;
        ssq[nt] = fmaf(ys, ys, ssq[nt]);
        ltw[(quad * 4 + rI) * 68 + nt * 16 + n] = ys;
      }
    const float* lrow = ltw + n * 68 + quad * 16;
    float4 va = *reinterpret_cast<const float4*>(lrow);
    float4 vb = *reinterpret_cast<const float4*>(lrow + 4);
    float4 vc = *reinterpret_cast<const float4*>(lrow + 8);
    float4 vd = *reinterpret_cast<const float4*>(lrow + 12);
    ushort_t* yo = y1 + (size_t)(rb + n) * 64 + quad * 16;
    *reinterpret_cast<uint4*>(yo) =
        make_uint4(pkhu(va.x, va.y), pkhu(va.z, va.w), pkhu(vb.x, vb.y), pkhu(vb.z, vb.w));
    *reinterpret_cast<uint4*>(yo + 8) =
        make_uint4(pkhu(vc.x, vc.y), pkhu(vc.z, vc.w), pkhu(vd.x, vd.y), pkhu(vd.z, vd.w));
  }
  float* stp = stats + (size_t)((blockIdx.x * 4 + w) & (NSLOT - 1)) * 64 * 2;
#pragma unroll
  for (int nt = 0; nt < 4; ++nt) {
    float s = ssum[nt], q = ssq[nt];
    s += __shfl_down(s, 16); q += __shfl_down(q, 16);
    s += __shfl_down(s, 32); q += __shfl_down(q, 32);
    if (l < 16) {
      atomicAdd(&stp[(size_t)(nt * 16 + l) * 2 + 0], s);
      atomicAdd(&stp[(size_t)(nt * 16 + l) * 2 + 1], q);
    }
  }
}

// ================================================================ gemm2 (MFMA)
__global__ __launch_bounds__(256) void gemm2_mfma(
    const ushort_t* __restrict__ y1, const float* __restrict__ bnp,
    const ushort_t* __restrict__ wB2, const float* __restrict__ bias2,
    float* __restrict__ stats, float* __restrict__ maxY, float* __restrict__ minY) {
  int t = threadIdx.x;
  int w = t >> 6, l = t & 63;
  int n = l & 15, quad = l >> 4;
  U4S8 bf[8][2];
#pragma unroll
  for (int nt = 0; nt < 8; ++nt)
#pragma unroll
    for (int kc = 0; kc < 2; ++kc)
      bf[nt][kc].u = *reinterpret_cast<const uint4*>(
          wB2 + (size_t)(nt * 16 + n) * 64 + kc * 32 + quad * 8);
  float4 scA[2], scB[2], shA[2], shB[2];
#pragma unroll
  for (int kc = 0; kc < 2; ++kc) {
    int cb = kc * 32 + quad * 8;
    scA[kc] = *reinterpret_cast<const float4*>(&bnp[128 + cb]);
    scB[kc] = *reinterpret_cast<const float4*>(&bnp[128 + cb + 4]);
    shA[kc] = *reinterpret_cast<const float4*>(&bnp[192 + cb]);
    shB[kc] = *reinterpret_cast<const float4*>(&bnp[192 + cb + 4]);
  }
  float b2v[8], ssum[8], ssq[8], mxv[8], mnv[8];
#pragma unroll
  for (int nt = 0; nt < 8; ++nt) {
    b2v[nt] = bias2[nt * 16 + n];
    ssum[nt] = 0.0f;
    ssq[nt] = 0.0f;
    mxv[nt] = -3.4e38f;
    mnv[nt] = 3.4e38f;
  }
  int rowbase0 = blockIdx.x * 1024 + w * 256;
#pragma unroll 1
  for (int tile = 0; tile < 16; ++tile) {
    int rb = rowbase0 + tile * 16;
    U4S8 af[2];
#pragma unroll
    for (int kc = 0; kc < 2; ++kc) {
      uint4 xv = *reinterpret_cast<const uint4*>(
          y1 + (size_t)(rb + n) * 64 + kc * 32 + quad * 8);
      af[kc].u = bn_relu_pack(xv, scA[kc], scB[kc], shA[kc], shB[kc]);
    }
    floatx4 acc[8];
#pragma unroll
    for (int nt = 0; nt < 8; ++nt) acc[nt] = floatx4{0.f, 0.f, 0.f, 0.f};
#pragma unroll
    for (int kc = 0; kc < 2; ++kc)
#pragma unroll
      for (int nt = 0; nt < 8; ++nt)
        acc[nt] = __builtin_amdgcn_mfma_f32_16x16x32_bf16(
            af[kc].v, bf[nt][kc].v, acc[nt], 0, 0, 0);
#pragma unroll
    for (int nt = 0; nt < 8; ++nt)
#pragma unroll
      for (int rI = 0; rI < 4; ++rI) {
        float ya = acc[nt][rI] + b2v[nt];
        ssum[nt] += ya;
        ssq[nt] = fmaf(ya, ya, ssq[nt]);
        mxv[nt] = fmaxf(mxv[nt], ya);
        mnv[nt] = fminf(mnv[nt], ya);
      }
    if (tile & 1) {
      int sidx = (rowbase0 >> 5) + (tile >> 1);
#pragma unroll
      for (int nt = 0; nt < 8; ++nt) {
        float mx = mxv[nt], mn = mnv[nt];
        mx = fmaxf(mx, __shfl_down(mx, 16));
        mn = fminf(mn, __shfl_down(mn, 16));
        mx = fmaxf(mx, __shfl_down(mx, 32));
        mn = fminf(mn, __shfl_down(mn, 32));
        if (l < 16) {
          maxY[(size_t)sidx * 128 + nt * 16 + l] = mx;
          minY[(size_t)sidx * 128 + nt * 16 + l] = mn;
        }
        mxv[nt] = -3.4e38f;
        mnv[nt] = 3.4e38f;
      }
    }
  }
  float* stp = stats + (size_t)((blockIdx.x * 4 + w) & (NSLOT - 1)) * 128 * 2;
#pragma unroll
  for (int nt = 0; nt < 8; ++nt) {
    float s = ssum[nt], q = ssq[nt];
    s += __shfl_down(s, 16); q += __shfl_down(q, 16);
    s += __shfl_down(s, 32); q += __shfl_down(q, 32);
    if (l < 16) {
      atomicAdd(&stp[(size_t)(nt * 16 + l) * 2 + 0], s);
      atomicAdd(&stp[(size_t)(nt * 16 + l) * 2 + 1], q);
    }
  }
}

// ---------------------------------------------------------------- BN finalize
__global__ void bn_finalize(const float* __restrict__ st, int cout,
                            const float* __restrict__ gamma,
                            const float* __restrict__ beta,
                            float* __restrict__ scale, float* __restrict__ shift) {
  int o = threadIdx.x;
  if (o >= cout) return;
  float s = 0.0f, q = 0.0f;
  for (int i = 0; i < NSLOT; ++i) {
    s += st[((size_t)i * cout + o) * 2 + 0];
    q += st[((size_t)i * cout + o) * 2 + 1];
  }
  float mean = s * (1.0f / CNT_F);
  float var = q * (1.0f / CNT_F) - mean * mean;
  float sc = gamma[o] / sqrtf(var + 1e-5f);
  scale[o] = sc;
  shift[o] = beta[o] - mean * sc;
}

// ---------------------------------------------------------------- pooling
__global__ __launch_bounds__(256) void pool_kernel(
    const float* __restrict__ maxY, const float* __restrict__ minY,
    const float* __restrict__ bnp, float* __restrict__ out) {
  __shared__ float tile[128 * 65];
  int b = blockIdx.x >> 4;
  int sbase = (blockIdx.x & 15) * 64;
  int t = threadIdx.x;
#pragma unroll 4
  for (int i = 0; i < 32; ++i) {
    int e = i * 256 + t;
    int sl = e >> 7, o = e & 127;
    float sc = bnp[256 + o], sh = bnp[384 + o];
    size_t g = ((size_t)(b * S_ + sbase + sl)) * 128 + o;
    float v = (sc >= 0.0f) ? maxY[g] : minY[g];
    tile[o * 65 + sl] = fmaxf(fmaf(v, sc, sh), 0.0f);
  }
  __syncthreads();
  int sl = t & 63;
  for (int o2 = t >> 6; o2 < 128; o2 += 4) {
    out[((size_t)(b * 128 + o2)) * S_ + sbase + sl] = tile[o2 * 65 + sl];
  }
}

// ---------------------------------------------------------------- launch
static inline size_t alup(size_t x) { return (x + 255) & ~(size_t)255; }

extern "C" void kernel_launch(void* const* d_in, const int* in_sizes, int n_in,
                              void* d_out, int out_size, void* d_ws, size_t ws_size,
                              hipStream_t stream) {
  (void)in_sizes; (void)n_in; (void)out_size;
  const float* xyz = (const float*)d_in[0];
  const float* points = (const float*)d_in[1];
  const float* w0 = (const float*)d_in[2];
  const float* b0 = (const float*)d_in[3];
  const float* g0 = (const float*)d_in[4];
  const float* be0 = (const float*)d_in[5];
  const float* w1 = (const float*)d_in[6];
  const float* b1 = (const float*)d_in[7];
  const float* g1 = (const float*)d_in[8];
  const float* be1 = (const float*)d_in[9];
  const float* w2 = (const float*)d_in[10];
  const float* b2 = (const float*)d_in[11];
  const float* g2 = (const float*)d_in[12];
  const float* be2 = (const float*)d_in[13];
  float* out_newxyz = (float*)d_out;
  float* out_newpts = out_newxyz + (size_t)B_ * S_ * 3;

  char* p = (char*)d_ws;
  int* pub = (int*)p;     p += alup((size_t)B_ * S_ * 4);
  float* ptn = (float*)p; p += alup((size_t)B_ * N_ * 4);
  float* st0 = (float*)p; p += (size_t)NSLOT * 64 * 2 * 4;
  float* st1 = (float*)p; p += (size_t)NSLOT * 64 * 2 * 4;
  float* st2 = (float*)p; p += (size_t)NSLOT * 128 * 2 * 4;
  float* bnp = (float*)p; p += alup(512 * 4);
  ushort_t* wB0 = (ushort_t*)p; p += alup(64 * 96 * 2);
  ushort_t* wB1 = (ushort_t*)p; p += alup(64 * 64 * 2);
  ushort_t* wB2 = (ushort_t*)p; p += alup(128 * 64 * 2);
  float* maxY = (float*)p; p += (size_t)B_ * S_ * 128 * 4;
  float* minY = (float*)p; p += (size_t)B_ * S_ * 128 * 4;
  ushort_t* y0 = (ushort_t*)p; p += (size_t)RWS * 64 * 2;
  ushort_t* y1 = (ushort_t*)p; p += (size_t)RWS * 64 * 2;
  if ((size_t)(p - (char*)d_ws) > ws_size) return;  // visible failure

  float* sc0 = bnp;       float* sh0 = bnp + 64;
  float* sc1 = bnp + 128; float* sh1 = bnp + 192;
  float* sc2 = bnp + 256; float* sh2 = bnp + 384;

  hipMemsetAsync(st0, 0, (size_t)NSLOT * (64 + 64 + 128) * 2 * 4, stream);
  hipMemsetAsync(pub, 0, (size_t)B_ * S_ * 4, stream);
  prep_all<<<256, 256, 0, stream>>>(xyz, ptn, w0, w1, w2, wB0, wB1, wB2);
  fused_kernel<<<NBLK, 256, 0, stream>>>(
      xyz, points, ptn, wB0, b0, pub, out_newxyz, y0, st0);
  bn_finalize<<<1, 128, 0, stream>>>(st0, 64, g0, be0, sc0, sh0);
  gemm1_mfma<<<RWS / 1024, 256, 0, stream>>>(y0, bnp, wB1, b1, y1, st1);
  bn_finalize<<<1, 128, 0, stream>>>(st1, 64, g1, be1, sc1, sh1);
  gemm2_mfma<<<RWS / 1024, 256, 0, stream>>>(y1, bnp, wB2, b2, st2, maxY, minY);
  bn_finalize<<<1, 128, 0, stream>>>(st2, 128, g2, be2, sc2, sh2);
  pool_kernel<<<B_ * (S_ / 64), 256, 0, stream>>>(maxY, minY, bnp, out_newpts);
}

// Round 5
// 856.217 us; speedup vs baseline: 1.4834x; 1.0632x over previous
//
#include <hip/hip_runtime.h>

#define B_ 16
#define N_ 4096
#define S_ 1024
#define K_ 32
#define NSLOT 128
#define CNT_F 524288.0f   // B*S*K
#define RWS 524288        // total rows = B*S*K

typedef unsigned short ushort_t;
typedef short short8 __attribute__((ext_vector_type(8)));
typedef float floatx4 __attribute__((ext_vector_type(4)));
union U4S8 { uint4 u; short8 v; };

__device__ __forceinline__ ushort_t f2bf(float f) {  // RNE
  unsigned u = __float_as_uint(f);
  unsigned r = (u + 0x7fffu + ((u >> 16) & 1u)) >> 16;
  return (ushort_t)r;
}
__device__ __forceinline__ unsigned pkrne(float a, float b) {
  return (unsigned)f2bf(a) | ((unsigned)f2bf(b) << 16);
}
__device__ __forceinline__ unsigned pkhu(float a, float b) {  // half-up pair
  return ((__float_as_uint(a) + 0x8000u) >> 16) |
         ((__float_as_uint(b) + 0x8000u) & 0xffff0000u);
}

// unpack 8 bf16, apply bn scale/shift + relu, repack as bf16 (half-up)
__device__ __forceinline__ uint4 bn_relu_pack(uint4 xv, float4 sca, float4 scb,
                                              float4 sha, float4 shb) {
  float x0 = __uint_as_float(xv.x << 16);
  float x1 = __uint_as_float(xv.x & 0xffff0000u);
  float x2 = __uint_as_float(xv.y << 16);
  float x3 = __uint_as_float(xv.y & 0xffff0000u);
  float x4 = __uint_as_float(xv.z << 16);
  float x5 = __uint_as_float(xv.z & 0xffff0000u);
  float x6 = __uint_as_float(xv.w << 16);
  float x7 = __uint_as_float(xv.w & 0xffff0000u);
  x0 = fmaxf(fmaf(x0, sca.x, sha.x), 0.0f);
  x1 = fmaxf(fmaf(x1, sca.y, sha.y), 0.0f);
  x2 = fmaxf(fmaf(x2, sca.z, sha.z), 0.0f);
  x3 = fmaxf(fmaf(x3, sca.w, sha.w), 0.0f);
  x4 = fmaxf(fmaf(x4, scb.x, shb.x), 0.0f);
  x5 = fmaxf(fmaf(x5, scb.y, shb.y), 0.0f);
  x6 = fmaxf(fmaf(x6, scb.z, shb.z), 0.0f);
  x7 = fmaxf(fmaf(x7, scb.w, shb.w), 0.0f);
  return make_uint4(pkhu(x0, x1), pkhu(x2, x3), pkhu(x4, x5), pkhu(x6, x7));
}

// ---------------------------------------------------------------- FPS params
#define FPS_T 256
#define FPS_P (N_ / FPS_T)   // 16
#define FPS_W (FPS_T / 64)   // 4

template <int CTRL>
__device__ __forceinline__ void dpp_max_u64(unsigned& hi, unsigned& lo) {
  unsigned h2 = (unsigned)__builtin_amdgcn_update_dpp(0, (int)hi, CTRL, 0xf, 0xf, true);
  unsigned l2 = (unsigned)__builtin_amdgcn_update_dpp(0, (int)lo, CTRL, 0xf, 0xf, true);
  bool take = (h2 > hi) || (h2 == hi && l2 > lo);
  hi = take ? h2 : hi;
  lo = take ? l2 : lo;
}

// ---------------------------------------------------------------- prep (xyzw pack + weights)
// xyzw[i] = (x, y, z, ||p||^2): one dwordx4 load per point in kNN (was 4 scalar)
__global__ __launch_bounds__(256) void prep_all(
    const float* __restrict__ xyz, float4* __restrict__ xyzw,
    const float* __restrict__ w0, const float* __restrict__ w1,
    const float* __restrict__ w2, ushort_t* __restrict__ wB0,
    ushort_t* __restrict__ wB1, ushort_t* __restrict__ wB2) {
  int i = blockIdx.x * 256 + threadIdx.x;  // < 65536 = B*N
  float x = xyz[(size_t)i * 3 + 0];
  float y = xyz[(size_t)i * 3 + 1];
  float z = xyz[(size_t)i * 3 + 2];
  float nrm = __fadd_rn(__fadd_rn(__fmul_rn(x, x), __fmul_rn(y, y)), __fmul_rn(z, z));
  xyzw[i] = make_float4(x, y, z, nrm);
  // wB0: [o][96] = [p-weights(64), xyz-weights(3), zeros(29)]
  if (i < 64 * 96) {
    int o = i / 96, c = i % 96;
    ushort_t v = 0;
    if (c < 64) v = f2bf(w0[o * 67 + 3 + c]);
    else if (c < 67) v = f2bf(w0[o * 67 + (c - 64)]);
    wB0[i] = v;
  }
  if (i < 64 * 64) wB1[i] = f2bf(w1[i]);
  if (i < 128 * 64) wB2[i] = f2bf(w2[i]);
}

// ================================================================ fused
// Grid 512 x 256 threads. LDS 55 KiB -> 2 blocks/CU by LDS; VGPR ~232
// (launch_bounds(256,1) = the ONLY config measured to give no-spill 232;
// any second-arg>=2 or 512-thread block pins arch-VGPR=128 -> ~790 MB
// scratch traffic, R2-R4). 232*2 = 464 <= 512 -> 2 waves/SIMD naturally,
// so all 512 blocks co-resident WITHOUT a launch-bounds occupancy cap.
// Blocks 0..15: FPS producer (one per batch), setprio(3) to win SIMD
// arbitration vs the co-resident consumer block.
// Blocks 16..511: consumer blocks, 4 waves each (1984 waves, 2/SIMD);
// per sample: spin for published index, kNN (register-resident u[64],
// float4 point loads, grouped-tournament argmin + DPP u64 reduce), then
// two 16-row gemm0 MFMA tiles (neighbor indices handed over via __shfl).
#define SMEM_BYTES 56320
#define NBLK 512
#define NCONS_W ((NBLK - B_) * 4)  // 1984 consumer waves

__global__ __launch_bounds__(256, 1) void fused_kernel(
    const float* __restrict__ xyz, const float* __restrict__ points,
    const float4* __restrict__ xyzw, const ushort_t* __restrict__ wB0,
    const float* __restrict__ bias0, int* __restrict__ pub,
    float* __restrict__ out_newxyz, ushort_t* __restrict__ y0,
    float* __restrict__ stats) {
  __shared__ __align__(16) char smem[SMEM_BYTES];
  int t = threadIdx.x;
  int w = t >> 6, l = t & 63;

  if (blockIdx.x < B_) {
    // ---------------- producer: FPS (identical math to R0 fps_kernel)
    float* xyz_s = (float*)smem;                                   // 49152 B
    int* idx_s = (int*)(smem + 49152);                             // 4096 B
    unsigned long long* keys_s = (unsigned long long*)(smem + 53248);  // 2*FPS_W
    int b = blockIdx.x;
    const float* xb = xyz + (size_t)b * N_ * 3;
    for (int i = t; i < N_ * 3; i += FPS_T) xyz_s[i] = xb[i];
    __syncthreads();
    float px[FPS_P], py[FPS_P], pz[FPS_P], dd[FPS_P];
#pragma unroll
    for (int j = 0; j < FPS_P; ++j) {
      int n = t + j * FPS_T;
      px[j] = xyz_s[n * 3 + 0];
      py[j] = xyz_s[n * 3 + 1];
      pz[j] = xyz_s[n * 3 + 2];
      dd[j] = 1e10f;
    }
    __builtin_amdgcn_s_setprio(3);  // beat co-resident consumer block
    int fi = 0;
#pragma unroll 1
    for (int s = 0; s < S_; ++s) {
      if (t == 0) {
        idx_s[s] = fi;
        __hip_atomic_store(&pub[(b << 10) + s], fi + 1, __ATOMIC_RELAXED,
                           __HIP_MEMORY_SCOPE_AGENT);
      }
      float cx = xyz_s[fi * 3 + 0], cy = xyz_s[fi * 3 + 1], cz = xyz_s[fi * 3 + 2];
      float bv = -1.0f;
      int bi = 0;
#pragma unroll
      for (int j = 0; j < FPS_P; ++j) {
        float dx = __fsub_rn(px[j], cx);
        float dy = __fsub_rn(py[j], cy);
        float dz = __fsub_rn(pz[j], cz);
        float d = __fadd_rn(__fadd_rn(__fmul_rn(dx, dx), __fmul_rn(dy, dy)),
                            __fmul_rn(dz, dz));
        d = fminf(dd[j], d);
        dd[j] = d;
        if (d > bv) { bv = d; bi = t + j * FPS_T; }
      }
      unsigned hi = __float_as_uint(bv);
      unsigned lo = (unsigned)(N_ - 1 - bi);
      dpp_max_u64<0x111>(hi, lo);
      dpp_max_u64<0x112>(hi, lo);
      dpp_max_u64<0x114>(hi, lo);
      dpp_max_u64<0x118>(hi, lo);
      dpp_max_u64<0x142>(hi, lo);
      dpp_max_u64<0x143>(hi, lo);
      unsigned whi = (unsigned)__builtin_amdgcn_readlane((int)hi, 63);
      unsigned wlo = (unsigned)__builtin_amdgcn_readlane((int)lo, 63);
      if ((t & 63) == 0)
        keys_s[(s & 1) * FPS_W + (t >> 6)] =
            ((unsigned long long)whi << 32) | wlo;
      __syncthreads();
      unsigned long long m = keys_s[(s & 1) * FPS_W + 0];
#pragma unroll
      for (int ww = 1; ww < FPS_W; ++ww) {
        unsigned long long k = keys_s[(s & 1) * FPS_W + ww];
        m = k > m ? k : m;
      }
      fi = (N_ - 1) - (int)(unsigned)(m & 0xFFFFFFFFULL);
    }
    __builtin_amdgcn_s_setprio(0);
    __syncthreads();
    for (int s = t; s < S_; s += FPS_T) {
      int i = idx_s[s];
      out_newxyz[((size_t)b * S_ + s) * 3 + 0] = xyz_s[i * 3 + 0];
      out_newxyz[((size_t)b * S_ + s) * 3 + 1] = xyz_s[i * 3 + 1];
      out_newxyz[((size_t)b * S_ + s) * 3 + 2] = xyz_s[i * 3 + 2];
    }
    return;
  }

  // ---------------- consumer: per-wave kNN + gemm0
  int n16 = l & 15, quad = l >> 4;
  U4S8 bf0[4][3];
  float b0v[4], ssum[4], ssq[4];
#pragma unroll
  for (int nt = 0; nt < 4; ++nt) {
#pragma unroll
    for (int kc = 0; kc < 3; ++kc)
      bf0[nt][kc].u = *reinterpret_cast<const uint4*>(
          wB0 + (size_t)(nt * 16 + n16) * 96 + kc * 32 + quad * 8);
    b0v[nt] = bias0[nt * 16 + n16];
    ssum[nt] = 0.0f;
    ssq[nt] = 0.0f;
  }
  float* ltw = (float*)(smem + w * (16 * 68 * 4));  // per-wave 4352 B bounce
  int wid = (blockIdx.x - B_) * 4 + w;              // 0..1983

#pragma unroll 1
  for (int r = wid; r < B_ * S_; r += NCONS_W) {
    int b = r & 15, s = r >> 4;
    int bs = (b << 10) + s;
    int pv = 0;
    if (l == 0) {
      int tries = 0;
      while ((pv = __hip_atomic_load(&pub[bs], __ATOMIC_RELAXED,
                                     __HIP_MEMORY_SCOPE_AGENT)) == 0) {
        __builtin_amdgcn_s_sleep(32);
        if (++tries > 65536) break;  // visible-failure valve, never trips normally
      }
    }
    pv = __shfl(pv, 0);
    int ci = pv - 1;
    if (ci < 0) ci = 0;  // valve tripped -> wrong-but-safe
    const float4* xw = xyzw + (size_t)b * N_;
    float4 c4 = xw[ci];
    float sx = c4.x, sy = c4.y, sz = c4.z;
    float nxn = c4.w;

    // ---- kNN distances (identical math; float4 point loads) ----
    unsigned u[64];
#pragma unroll
    for (int j = 0; j < 64; ++j) {
      int nn = j * 64 + l;
      float4 v = xw[nn];
      float e = __fadd_rn(__fadd_rn(__fmul_rn(sx, v.x), __fmul_rn(sy, v.y)),
                          __fmul_rn(sz, v.z));
      float d = __fadd_rn(__fadd_rn(nxn, v.w), __fmul_rn(-2.0f, e));
      int sb = __float_as_int(d);
      u[j] = (sb < 0) ? ~((unsigned)sb) : (((unsigned)sb) | 0x80000000u);
    }
    // ---- top-K selection: grouped tournament + DPP u64 min-reduce ----
    unsigned keep = 0;
#pragma unroll 1
    for (int p = 0; p < K_; ++p) {
      // per-lane argmin over u[0..63], lowest j wins ties (strict <, left-kept)
      unsigned gv[8], gj_[8];
#pragma unroll
      for (int g = 0; g < 8; ++g) {
        unsigned bv = u[g * 8];
        unsigned bj = (unsigned)(g * 8);
#pragma unroll
        for (int j2 = 1; j2 < 8; ++j2) {
          unsigned uu = u[g * 8 + j2];
          bool tk = uu < bv;
          bv = tk ? uu : bv;
          bj = tk ? (unsigned)(g * 8 + j2) : bj;
        }
        gv[g] = bv;
        gj_[g] = bj;
      }
#pragma unroll
      for (int st = 4; st >= 1; st >>= 1)
#pragma unroll
        for (int i2 = 0; i2 < 4; ++i2) {
          if (i2 < st) {
            bool tk = gv[i2 + st] < gv[i2];  // tie -> keep left (lower j)
            gv[i2] = tk ? gv[i2 + st] : gv[i2];
            gj_[i2] = tk ? gj_[i2 + st] : gj_[i2];
          }
        }
      // wave min on (value, global-idx): max-reduce of inverted keys via DPP
      unsigned hi = ~gv[0];
      unsigned lo = ~(gj_[0] * 64u + (unsigned)l);
      dpp_max_u64<0x111>(hi, lo);
      dpp_max_u64<0x112>(hi, lo);
      dpp_max_u64<0x114>(hi, lo);
      dpp_max_u64<0x118>(hi, lo);
      dpp_max_u64<0x142>(hi, lo);
      dpp_max_u64<0x143>(hi, lo);
      unsigned wlo = (unsigned)__builtin_amdgcn_readlane((int)lo, 63);
      unsigned gn = ~wlo;  // global index of winner (min value, then min idx)
      if (l == p) keep = gn;
      if ((gn & 63u) == (unsigned)l) {
        int gj = (int)(gn >> 6);
#pragma unroll
        for (int j = 0; j < 64; ++j)
          if (j == gj) u[j] = 0xFFFFFFFFu;
      }
    }

    // ---- gemm0: two 16-row MFMA tiles for this sample ----
#pragma unroll 1
    for (int t2 = 0; t2 < 2; ++t2) {
      int rb = bs * 32 + t2 * 16;
      int idxr = __shfl((int)keep, t2 * 16 + n16);
      const float* pbase = points + (size_t)b * N_ * 64 + (size_t)idxr * 64;
      U4S8 af[3];
#pragma unroll
      for (int kc = 0; kc < 2; ++kc) {
        float4 va = *reinterpret_cast<const float4*>(pbase + kc * 32 + quad * 8);
        float4 vb = *reinterpret_cast<const float4*>(pbase + kc * 32 + quad * 8 + 4);
        af[kc].u = make_uint4(pkrne(va.x, va.y), pkrne(va.z, va.w),
                              pkrne(vb.x, vb.y), pkrne(vb.z, vb.w));
      }
      if (quad == 0) {
        float4 p4 = xw[idxr];
        float dx = __fsub_rn(p4.x, sx);
        float dy = __fsub_rn(p4.y, sy);
        float dz = __fsub_rn(p4.z, sz);
        af[2].u = make_uint4(pkrne(dx, dy), (unsigned)f2bf(dz), 0u, 0u);
      } else {
        af[2].u = make_uint4(0u, 0u, 0u, 0u);
      }
      floatx4 acc[4];
#pragma unroll
      for (int nt = 0; nt < 4; ++nt) acc[nt] = floatx4{0.f, 0.f, 0.f, 0.f};
#pragma unroll
      for (int kc = 0; kc < 3; ++kc)
#pragma unroll
        for (int nt = 0; nt < 4; ++nt)
          acc[nt] = __builtin_amdgcn_mfma_f32_16x16x32_bf16(
              af[kc].v, bf0[nt][kc].v, acc[nt], 0, 0, 0);
#pragma unroll
      for (int nt = 0; nt < 4; ++nt)
#pragma unroll
        for (int rI = 0; rI < 4; ++rI) {
          float ys = acc[nt][rI] + b0v[nt];
          ssum[nt] += ys;
          ssq[nt] = fmaf(ys, ys, ssq[nt]);
          ltw[(quad * 4 + rI) * 68 + nt * 16 + n16] = ys;
        }
      const float* lrow = ltw + n16 * 68 + quad * 16;
      float4 va = *reinterpret_cast<const float4*>(lrow);
      float4 vb = *reinterpret_cast<const float4*>(lrow + 4);
      float4 vc = *reinterpret_cast<const float4*>(lrow + 8);
      float4 vd = *reinterpret_cast<const float4*>(lrow + 12);
      ushort_t* yo = y0 + (size_t)(rb + n16) * 64 + quad * 16;
      *reinterpret_cast<uint4*>(yo) =
          make_uint4(pkhu(va.x, va.y), pkhu(va.z, va.w), pkhu(vb.x, vb.y), pkhu(vb.z, vb.w));
      *reinterpret_cast<uint4*>(yo + 8) =
          make_uint4(pkhu(vc.x, vc.y), pkhu(vc.z, vc.w), pkhu(vd.x, vd.y), pkhu(vd.z, vd.w));
    }
  }

  // ---- stats flush (once per wave) ----
  float* stp = stats + (size_t)(wid & (NSLOT - 1)) * 64 * 2;
#pragma unroll
  for (int nt = 0; nt < 4; ++nt) {
    float s = ssum[nt], q = ssq[nt];
    s += __shfl_down(s, 16); q += __shfl_down(q, 16);
    s += __shfl_down(s, 32); q += __shfl_down(q, 32);
    if (l < 16) {
      atomicAdd(&stp[(size_t)(nt * 16 + l) * 2 + 0], s);
      atomicAdd(&stp[(size_t)(nt * 16 + l) * 2 + 1], q);
    }
  }
}

// ================================================================ gemm1 (MFMA)
__global__ __launch_bounds__(256) void gemm1_mfma(
    const ushort_t* __restrict__ y0, const float* __restrict__ bnp,
    const ushort_t* __restrict__ wB1, const float* __restrict__ bias1,
    ushort_t* __restrict__ y1, float* __restrict__ stats) {
  __shared__ __align__(16) float lt[4][16 * 68];
  int t = threadIdx.x;
  int w = t >> 6, l = t & 63;
  int n = l & 15, quad = l >> 4;
  U4S8 bf[4][2];
#pragma unroll
  for (int nt = 0; nt < 4; ++nt)
#pragma unroll
    for (int kc = 0; kc < 2; ++kc)
      bf[nt][kc].u = *reinterpret_cast<const uint4*>(
          wB1 + (size_t)(nt * 16 + n) * 64 + kc * 32 + quad * 8);
  float4 scA[2], scB[2], shA[2], shB[2];
#pragma unroll
  for (int kc = 0; kc < 2; ++kc) {
    int cb = kc * 32 + quad * 8;
    scA[kc] = *reinterpret_cast<const float4*>(&bnp[cb]);
    scB[kc] = *reinterpret_cast<const float4*>(&bnp[cb + 4]);
    shA[kc] = *reinterpret_cast<const float4*>(&bnp[64 + cb]);
    shB[kc] = *reinterpret_cast<const float4*>(&bnp[64 + cb + 4]);
  }
  float b1v[4], ssum[4], ssq[4];
#pragma unroll
  for (int nt = 0; nt < 4; ++nt) {
    b1v[nt] = bias1[nt * 16 + n];
    ssum[nt] = 0.0f;
    ssq[nt] = 0.0f;
  }
  int rowbase0 = blockIdx.x * 1024 + w * 256;
  float* ltw = lt[w];
#pragma unroll 1
  for (int tile = 0; tile < 16; ++tile) {
    int rb = rowbase0 + tile * 16;
    U4S8 af[2];
#pragma unroll
    for (int kc = 0; kc < 2; ++kc) {
      uint4 xv = *reinterpret_cast<const uint4*>(
          y0 + (size_t)(rb + n) * 64 + kc * 32 + quad * 8);
      af[kc].u = bn_relu_pack(xv, scA[kc], scB[kc], shA[kc], shB[kc]);
    }
    floatx4 acc[4];
#pragma unroll
    for (int nt = 0; nt < 4; ++nt) acc[nt] = floatx4{0.f, 0.f, 0.f, 0.f};
#pragma unroll
    for (int kc = 0; kc < 2; ++kc)
#pragma unroll
      for (int nt = 0; nt < 4; ++nt)
        acc[nt] = __builtin_amdgcn_mfma_f32_16x16x32_bf16(
            af[kc].v, bf[nt][kc].v, acc[nt], 0, 0, 0);
#pragma unroll
    for (int nt = 0; nt < 4; ++nt)
#pragma unroll
      for (int rI = 0; rI < 4; ++rI) {
        float ys = acc[nt][rI] + b1v[nt];
        ssum[nt] += ys;
        ssq[nt] = fmaf(ys, ys, ssq[nt]);
        ltw[(quad * 4 + rI) * 68 + nt * 16 + n] = ys;
      }
    const float* lrow = ltw + n * 68 + quad * 16;
    float4 va = *reinterpret_cast<const float4*>(lrow);
    float4 vb = *reinterpret_cast<const float4*>(lrow + 4);
    float4 vc = *reinterpret_cast<const float4*>(lrow + 8);
    float4 vd = *reinterpret_cast<const float4*>(lrow + 12);
    ushort_t* yo = y1 + (size_t)(rb + n) * 64 + quad * 16;
    *reinterpret_cast<uint4*>(yo) =
        make_uint4(pkhu(va.x, va.y), pkhu(va.z, va.w), pkhu(vb.x, vb.y), pkhu(vb.z, vb.w));
    *reinterpret_cast<uint4*>(yo + 8) =
        make_uint4(pkhu(vc.x, vc.y), pkhu(vc.z, vc.w), pkhu(vd.x, vd.y), pkhu(vd.z, vd.w));
  }
  float* stp = stats + (size_t)((blockIdx.x * 4 + w) & (NSLOT - 1)) * 64 * 2;
#pragma unroll
  for (int nt = 0; nt < 4; ++nt) {
    float s = ssum[nt], q = ssq[nt];
    s += __shfl_down(s, 16); q += __shfl_down(q, 16);
    s += __shfl_down(s, 32); q += __shfl_down(q, 32);
    if (l < 16) {
      atomicAdd(&stp[(size_t)(nt * 16 + l) * 2 + 0], s);
      atomicAdd(&stp[(size_t)(nt * 16 + l) * 2 + 1], q);
    }
  }
}

// ================================================================ gemm2 (MFMA)
__global__ __launch_bounds__(256) void gemm2_mfma(
    const ushort_t* __restrict__ y1, const float* __restrict__ bnp,
    const ushort_t* __restrict__ wB2, const float* __restrict__ bias2,
    float* __restrict__ stats, float* __restrict__ maxY, float* __restrict__ minY) {
  int t = threadIdx.x;
  int w = t >> 6, l = t & 63;
  int n = l & 15, quad = l >> 4;
  U4S8 bf[8][2];
#pragma unroll
  for (int nt = 0; nt < 8; ++nt)
#pragma unroll
    for (int kc = 0; kc < 2; ++kc)
      bf[nt][kc].u = *reinterpret_cast<const uint4*>(
          wB2 + (size_t)(nt * 16 + n) * 64 + kc * 32 + quad * 8);
  float4 scA[2], scB[2], shA[2], shB[2];
#pragma unroll
  for (int kc = 0; kc < 2; ++kc) {
    int cb = kc * 32 + quad * 8;
    scA[kc] = *reinterpret_cast<const float4*>(&bnp[128 + cb]);
    scB[kc] = *reinterpret_cast<const float4*>(&bnp[128 + cb + 4]);
    shA[kc] = *reinterpret_cast<const float4*>(&bnp[192 + cb]);
    shB[kc] = *reinterpret_cast<const float4*>(&bnp[192 + cb + 4]);
  }
  float b2v[8], ssum[8], ssq[8], mxv[8], mnv[8];
#pragma unroll
  for (int nt = 0; nt < 8; ++nt) {
    b2v[nt] = bias2[nt * 16 + n];
    ssum[nt] = 0.0f;
    ssq[nt] = 0.0f;
    mxv[nt] = -3.4e38f;
    mnv[nt] = 3.4e38f;
  }
  int rowbase0 = blockIdx.x * 1024 + w * 256;
#pragma unroll 1
  for (int tile = 0; tile < 16; ++tile) {
    int rb = rowbase0 + tile * 16;
    U4S8 af[2];
#pragma unroll
    for (int kc = 0; kc < 2; ++kc) {
      uint4 xv = *reinterpret_cast<const uint4*>(
          y1 + (size_t)(rb + n) * 64 + kc * 32 + quad * 8);
      af[kc].u = bn_relu_pack(xv, scA[kc], scB[kc], shA[kc], shB[kc]);
    }
    floatx4 acc[8];
#pragma unroll
    for (int nt = 0; nt < 8; ++nt) acc[nt] = floatx4{0.f, 0.f, 0.f, 0.f};
#pragma unroll
    for (int kc = 0; kc < 2; ++kc)
#pragma unroll
      for (int nt = 0; nt < 8; ++nt)
        acc[nt] = __builtin_amdgcn_mfma_f32_16x16x32_bf16(
            af[kc].v, bf[nt][kc].v, acc[nt], 0, 0, 0);
#pragma unroll
    for (int nt = 0; nt < 8; ++nt)
#pragma unroll
      for (int rI = 0; rI < 4; ++rI) {
        float ya = acc[nt][rI] + b2v[nt];
        ssum[nt] += ya;
        ssq[nt] = fmaf(ya, ya, ssq[nt]);
        mxv[nt] = fmaxf(mxv[nt], ya);
        mnv[nt] = fminf(mnv[nt], ya);
      }
    if (tile & 1) {
      int sidx = (rowbase0 >> 5) + (tile >> 1);
#pragma unroll
      for (int nt = 0; nt < 8; ++nt) {
        float mx = mxv[nt], mn = mnv[nt];
        mx = fmaxf(mx, __shfl_down(mx, 16));
        mn = fminf(mn, __shfl_down(mn, 16));
        mx = fmaxf(mx, __shfl_down(mx, 32));
        mn = fminf(mn, __shfl_down(mn, 32));
        if (l < 16) {
          maxY[(size_t)sidx * 128 + nt * 16 + l] = mx;
          minY[(size_t)sidx * 128 + nt * 16 + l] = mn;
        }
        mxv[nt] = -3.4e38f;
        mnv[nt] = 3.4e38f;
      }
    }
  }
  float* stp = stats + (size_t)((blockIdx.x * 4 + w) & (NSLOT - 1)) * 128 * 2;
#pragma unroll
  for (int nt = 0; nt < 8; ++nt) {
    float s = ssum[nt], q = ssq[nt];
    s += __shfl_down(s, 16); q += __shfl_down(q, 16);
    s += __shfl_down(s, 32); q += __shfl_down(q, 32);
    if (l < 16) {
      atomicAdd(&stp[(size_t)(nt * 16 + l) * 2 + 0], s);
      atomicAdd(&stp[(size_t)(nt * 16 + l) * 2 + 1], q);
    }
  }
}

// ---------------------------------------------------------------- BN finalize
__global__ void bn_finalize(const float* __restrict__ st, int cout,
                            const float* __restrict__ gamma,
                            const float* __restrict__ beta,
                            float* __restrict__ scale, float* __restrict__ shift) {
  int o = threadIdx.x;
  if (o >= cout) return;
  float s = 0.0f, q = 0.0f;
  for (int i = 0; i < NSLOT; ++i) {
    s += st[((size_t)i * cout + o) * 2 + 0];
    q += st[((size_t)i * cout + o) * 2 + 1];
  }
  float mean = s * (1.0f / CNT_F);
  float var = q * (1.0f / CNT_F) - mean * mean;
  float sc = gamma[o] / sqrtf(var + 1e-5f);
  scale[o] = sc;
  shift[o] = beta[o] - mean * sc;
}

// ---------------------------------------------------------------- pooling
__global__ __launch_bounds__(256) void pool_kernel(
    const float* __restrict__ maxY, const float* __restrict__ minY,
    const float* __restrict__ bnp, float* __restrict__ out) {
  __shared__ float tile[128 * 65];
  int b = blockIdx.x >> 4;
  int sbase = (blockIdx.x & 15) * 64;
  int t = threadIdx.x;
#pragma unroll 4
  for (int i = 0; i < 32; ++i) {
    int e = i * 256 + t;
    int sl = e >> 7, o = e & 127;
    float sc = bnp[256 + o], sh = bnp[384 + o];
    size_t g = ((size_t)(b * S_ + sbase + sl)) * 128 + o;
    float v = (sc >= 0.0f) ? maxY[g] : minY[g];
    tile[o * 65 + sl] = fmaxf(fmaf(v, sc, sh), 0.0f);
  }
  __syncthreads();
  int sl = t & 63;
  for (int o2 = t >> 6; o2 < 128; o2 += 4) {
    out[((size_t)(b * 128 + o2)) * S_ + sbase + sl] = tile[o2 * 65 + sl];
  }
}

// ---------------------------------------------------------------- launch
static inline size_t alup(size_t x) { return (x + 255) & ~(size_t)255; }

extern "C" void kernel_launch(void* const* d_in, const int* in_sizes, int n_in,
                              void* d_out, int out_size, void* d_ws, size_t ws_size,
                              hipStream_t stream) {
  (void)in_sizes; (void)n_in; (void)out_size;
  const float* xyz = (const float*)d_in[0];
  const float* points = (const float*)d_in[1];
  const float* w0 = (const float*)d_in[2];
  const float* b0 = (const float*)d_in[3];
  const float* g0 = (const float*)d_in[4];
  const float* be0 = (const float*)d_in[5];
  const float* w1 = (const float*)d_in[6];
  const float* b1 = (const float*)d_in[7];
  const float* g1 = (const float*)d_in[8];
  const float* be1 = (const float*)d_in[9];
  const float* w2 = (const float*)d_in[10];
  const float* b2 = (const float*)d_in[11];
  const float* g2 = (const float*)d_in[12];
  const float* be2 = (const float*)d_in[13];
  float* out_newxyz = (float*)d_out;
  float* out_newpts = out_newxyz + (size_t)B_ * S_ * 3;

  char* p = (char*)d_ws;
  int* pub = (int*)p;      p += alup((size_t)B_ * S_ * 4);
  float4* xyzw = (float4*)p; p += alup((size_t)B_ * N_ * 16);
  float* st0 = (float*)p;  p += (size_t)NSLOT * 64 * 2 * 4;
  float* st1 = (float*)p;  p += (size_t)NSLOT * 64 * 2 * 4;
  float* st2 = (float*)p;  p += (size_t)NSLOT * 128 * 2 * 4;
  float* bnp = (float*)p;  p += alup(512 * 4);
  ushort_t* wB0 = (ushort_t*)p; p += alup(64 * 96 * 2);
  ushort_t* wB1 = (ushort_t*)p; p += alup(64 * 64 * 2);
  ushort_t* wB2 = (ushort_t*)p; p += alup(128 * 64 * 2);
  float* maxY = (float*)p; p += (size_t)B_ * S_ * 128 * 4;
  float* minY = (float*)p; p += (size_t)B_ * S_ * 128 * 4;
  ushort_t* y0 = (ushort_t*)p; p += (size_t)RWS * 64 * 2;
  ushort_t* y1 = (ushort_t*)p; p += (size_t)RWS * 64 * 2;
  if ((size_t)(p - (char*)d_ws) > ws_size) return;  // visible failure

  float* sc0 = bnp;       float* sh0 = bnp + 64;
  float* sc1 = bnp + 128; float* sh1 = bnp + 192;
  float* sc2 = bnp + 256; float* sh2 = bnp + 384;

  hipMemsetAsync(st0, 0, (size_t)NSLOT * (64 + 64 + 128) * 2 * 4, stream);
  hipMemsetAsync(pub, 0, (size_t)B_ * S_ * 4, stream);
  prep_all<<<256, 256, 0, stream>>>(xyz, xyzw, w0, w1, w2, wB0, wB1, wB2);
  fused_kernel<<<NBLK, 256, 0, stream>>>(
      xyz, points, xyzw, wB0, b0, pub, out_newxyz, y0, st0);
  bn_finalize<<<1, 128, 0, stream>>>(st0, 64, g0, be0, sc0, sh0);
  gemm1_mfma<<<RWS / 1024, 256, 0, stream>>>(y0, bnp, wB1, b1, y1, st1);
  bn_finalize<<<1, 128, 0, stream>>>(st1, 64, g1, be1, sc1, sh1);
  gemm2_mfma<<<RWS / 1024, 256, 0, stream>>>(y1, bnp, wB2, b2, st2, maxY, minY);
  bn_finalize<<<1, 128, 0, stream>>>(st2, 128, g2, be2, sc2, sh2);
  pool_kernel<<<B_ * (S_ / 64), 256, 0, stream>>>(maxY, minY, bnp, out_newpts);
}

// Round 6
// 784.689 us; speedup vs baseline: 1.6186x; 1.0912x over previous
//
#include <hip/hip_runtime.h>

#define B_ 16
#define N_ 4096
#define S_ 1024
#define K_ 32
#define NSLOT 128
#define CNT_F 524288.0f   // B*S*K
#define RWS 524288        // total rows = B*S*K

typedef unsigned short ushort_t;
typedef short short8 __attribute__((ext_vector_type(8)));
typedef float floatx4 __attribute__((ext_vector_type(4)));
union U4S8 { uint4 u; short8 v; };

__device__ __forceinline__ ushort_t f2bf(float f) {  // RNE
  unsigned u = __float_as_uint(f);
  unsigned r = (u + 0x7fffu + ((u >> 16) & 1u)) >> 16;
  return (ushort_t)r;
}
__device__ __forceinline__ unsigned pkrne(float a, float b) {
  return (unsigned)f2bf(a) | ((unsigned)f2bf(b) << 16);
}
__device__ __forceinline__ unsigned pkhu(float a, float b) {  // half-up pair
  return ((__float_as_uint(a) + 0x8000u) >> 16) |
         ((__float_as_uint(b) + 0x8000u) & 0xffff0000u);
}

// unpack 8 bf16, apply bn scale/shift + relu, repack as bf16 (half-up)
__device__ __forceinline__ uint4 bn_relu_pack(uint4 xv, float4 sca, float4 scb,
                                              float4 sha, float4 shb) {
  float x0 = __uint_as_float(xv.x << 16);
  float x1 = __uint_as_float(xv.x & 0xffff0000u);
  float x2 = __uint_as_float(xv.y << 16);
  float x3 = __uint_as_float(xv.y & 0xffff0000u);
  float x4 = __uint_as_float(xv.z << 16);
  float x5 = __uint_as_float(xv.z & 0xffff0000u);
  float x6 = __uint_as_float(xv.w << 16);
  float x7 = __uint_as_float(xv.w & 0xffff0000u);
  x0 = fmaxf(fmaf(x0, sca.x, sha.x), 0.0f);
  x1 = fmaxf(fmaf(x1, sca.y, sha.y), 0.0f);
  x2 = fmaxf(fmaf(x2, sca.z, sha.z), 0.0f);
  x3 = fmaxf(fmaf(x3, sca.w, sha.w), 0.0f);
  x4 = fmaxf(fmaf(x4, scb.x, shb.x), 0.0f);
  x5 = fmaxf(fmaf(x5, scb.y, shb.y), 0.0f);
  x6 = fmaxf(fmaf(x6, scb.z, shb.z), 0.0f);
  x7 = fmaxf(fmaf(x7, scb.w, shb.w), 0.0f);
  return make_uint4(pkhu(x0, x1), pkhu(x2, x3), pkhu(x4, x5), pkhu(x6, x7));
}

// ---------------------------------------------------------------- FPS params
#define FPS_T 256
#define FPS_P (N_ / FPS_T)   // 16
#define FPS_W (FPS_T / 64)   // 4

// ---- fast wave argmax: two-phase u32 DPP max (value, then candidate) ----
// Phase split is EXACTLY equivalent to the old lexicographic u64 max:
// phase1 finds max value; phase2 maxes (inv-index) over value-winners only
// (losers contribute 0, which can never beat a winner's candidate).
template <int CTRL>
__device__ __forceinline__ unsigned dpp_max_u32(unsigned v) {
  unsigned o = (unsigned)__builtin_amdgcn_update_dpp(0, (int)v, CTRL, 0xf, 0xf, true);
  return v > o ? v : o;
}
__device__ __forceinline__ unsigned wave_max_u32(unsigned v) {
  v = dpp_max_u32<0x111>(v);
  v = dpp_max_u32<0x112>(v);
  v = dpp_max_u32<0x114>(v);
  v = dpp_max_u32<0x118>(v);
  v = dpp_max_u32<0x142>(v);
  v = dpp_max_u32<0x143>(v);
  return (unsigned)__builtin_amdgcn_readlane((int)v, 63);
}

// ---------------------------------------------------------------- prep (xyzw pack + weights)
// xyzw[i] = (x, y, z, ||p||^2): one dwordx4 load per point in kNN (was 4 scalar)
__global__ __launch_bounds__(256) void prep_all(
    const float* __restrict__ xyz, float4* __restrict__ xyzw,
    const float* __restrict__ w0, const float* __restrict__ w1,
    const float* __restrict__ w2, ushort_t* __restrict__ wB0,
    ushort_t* __restrict__ wB1, ushort_t* __restrict__ wB2) {
  int i = blockIdx.x * 256 + threadIdx.x;  // < 65536 = B*N
  float x = xyz[(size_t)i * 3 + 0];
  float y = xyz[(size_t)i * 3 + 1];
  float z = xyz[(size_t)i * 3 + 2];
  float nrm = __fadd_rn(__fadd_rn(__fmul_rn(x, x), __fmul_rn(y, y)), __fmul_rn(z, z));
  xyzw[i] = make_float4(x, y, z, nrm);
  // wB0: [o][96] = [p-weights(64), xyz-weights(3), zeros(29)]
  if (i < 64 * 96) {
    int o = i / 96, c = i % 96;
    ushort_t v = 0;
    if (c < 64) v = f2bf(w0[o * 67 + 3 + c]);
    else if (c < 67) v = f2bf(w0[o * 67 + (c - 64)]);
    wB0[i] = v;
  }
  if (i < 64 * 64) wB1[i] = f2bf(w1[i]);
  if (i < 128 * 64) wB2[i] = f2bf(w2[i]);
}

// ================================================================ fused
// Grid 512 x 256 threads. LDS 55 KiB -> 2 blocks/CU by LDS; VGPR ~112
// measured (launch_bounds(256,1) only; any second-arg>=2 or 512-thread
// block pins arch-VGPR=128 -> spills, R2-R4). All 512 blocks co-resident
// => deadlock-free producer/consumer handshake.
// Blocks 0..15: FPS producer (one per batch), setprio(3).
// Blocks 16..511: consumer blocks, 4 waves each (1984 waves, 2/SIMD).
#define SMEM_BYTES 56320
#define NBLK 512
#define NCONS_W ((NBLK - B_) * 4)  // 1984 consumer waves

__global__ __launch_bounds__(256, 1) void fused_kernel(
    const float* __restrict__ xyz, const float* __restrict__ points,
    const float4* __restrict__ xyzw, const ushort_t* __restrict__ wB0,
    const float* __restrict__ bias0, int* __restrict__ pub,
    float* __restrict__ out_newxyz, ushort_t* __restrict__ y0,
    float* __restrict__ stats) {
  __shared__ __align__(16) char smem[SMEM_BYTES];
  int t = threadIdx.x;
  int w = t >> 6, l = t & 63;

  if (blockIdx.x < B_) {
    // ---------------- producer: FPS (identical selection math; fast reduce)
    float* xyz_s = (float*)smem;                                   // 49152 B
    int* idx_s = (int*)(smem + 49152);                             // 4096 B
    unsigned long long* keys_s = (unsigned long long*)(smem + 53248);  // 2*FPS_W
    int b = blockIdx.x;
    const float* xb = xyz + (size_t)b * N_ * 3;
    for (int i = t; i < N_ * 3; i += FPS_T) xyz_s[i] = xb[i];
    __syncthreads();
    float px[FPS_P], py[FPS_P], pz[FPS_P], dd[FPS_P];
#pragma unroll
    for (int j = 0; j < FPS_P; ++j) {
      int n = t + j * FPS_T;
      px[j] = xyz_s[n * 3 + 0];
      py[j] = xyz_s[n * 3 + 1];
      pz[j] = xyz_s[n * 3 + 2];
      dd[j] = 1e10f;
    }
    __builtin_amdgcn_s_setprio(3);  // beat co-resident consumer block
    int fi = 0;
#pragma unroll 1
    for (int s = 0; s < S_; ++s) {
      if (t == 0) {
        idx_s[s] = fi;
        __hip_atomic_store(&pub[(b << 10) + s], fi + 1, __ATOMIC_RELAXED,
                           __HIP_MEMORY_SCOPE_AGENT);
      }
      float cx = xyz_s[fi * 3 + 0], cy = xyz_s[fi * 3 + 1], cz = xyz_s[fi * 3 + 2];
      float bv = -1.0f;
      int bi = 0;
#pragma unroll
      for (int j = 0; j < FPS_P; ++j) {
        float dx = __fsub_rn(px[j], cx);
        float dy = __fsub_rn(py[j], cy);
        float dz = __fsub_rn(pz[j], cz);
        float d = __fadd_rn(__fadd_rn(__fmul_rn(dx, dx), __fmul_rn(dy, dy)),
                            __fmul_rn(dz, dz));
        d = fminf(dd[j], d);
        dd[j] = d;
        if (d > bv) { bv = d; bi = t + j * FPS_T; }
      }
      // two-phase wave argmax (exact; bv >= 0 after first point so float
      // bits are u32-monotone)
      unsigned hi = __float_as_uint(bv);
      unsigned vmax = wave_max_u32(hi);
      unsigned cand = (hi == vmax) ? (unsigned)(N_ - 1 - bi) : 0u;
      unsigned cmax = wave_max_u32(cand);
      if ((t & 63) == 0)
        keys_s[(s & 1) * FPS_W + (t >> 6)] =
            ((unsigned long long)vmax << 32) | cmax;
      __syncthreads();
      unsigned long long m = keys_s[(s & 1) * FPS_W + 0];
#pragma unroll
      for (int ww = 1; ww < FPS_W; ++ww) {
        unsigned long long k = keys_s[(s & 1) * FPS_W + ww];
        m = k > m ? k : m;
      }
      fi = (N_ - 1) - (int)(unsigned)(m & 0xFFFFFFFFULL);
    }
    __builtin_amdgcn_s_setprio(0);
    __syncthreads();
    for (int s = t; s < S_; s += FPS_T) {
      int i = idx_s[s];
      out_newxyz[((size_t)b * S_ + s) * 3 + 0] = xyz_s[i * 3 + 0];
      out_newxyz[((size_t)b * S_ + s) * 3 + 1] = xyz_s[i * 3 + 1];
      out_newxyz[((size_t)b * S_ + s) * 3 + 2] = xyz_s[i * 3 + 2];
    }
    return;
  }

  // ---------------- consumer: per-wave kNN + gemm0
  int n16 = l & 15, quad = l >> 4;
  U4S8 bf0[4][3];
  float b0v[4], ssum[4], ssq[4];
#pragma unroll
  for (int nt = 0; nt < 4; ++nt) {
#pragma unroll
    for (int kc = 0; kc < 3; ++kc)
      bf0[nt][kc].u = *reinterpret_cast<const uint4*>(
          wB0 + (size_t)(nt * 16 + n16) * 96 + kc * 32 + quad * 8);
    b0v[nt] = bias0[nt * 16 + n16];
    ssum[nt] = 0.0f;
    ssq[nt] = 0.0f;
  }
  float* ltw = (float*)(smem + w * (16 * 68 * 4));  // per-wave 4352 B bounce
  int wid = (blockIdx.x - B_) * 4 + w;              // 0..1983

#pragma unroll 1
  for (int r = wid; r < B_ * S_; r += NCONS_W) {
    int b = r & 15, s = r >> 4;
    int bs = (b << 10) + s;
    int pv = 0;
    if (l == 0) {
      int tries = 0;
      while ((pv = __hip_atomic_load(&pub[bs], __ATOMIC_RELAXED,
                                     __HIP_MEMORY_SCOPE_AGENT)) == 0) {
        __builtin_amdgcn_s_sleep(32);
        if (++tries > 65536) break;  // visible-failure valve, never trips normally
      }
    }
    pv = __shfl(pv, 0);
    int ci = pv - 1;
    if (ci < 0) ci = 0;  // valve tripped -> wrong-but-safe
    const float4* xw = xyzw + (size_t)b * N_;
    float4 c4 = xw[ci];
    float sx = c4.x, sy = c4.y, sz = c4.z;
    float nxn = c4.w;

    // ---- kNN distances (identical math; float4 point loads) ----
    unsigned u[64];
#pragma unroll
    for (int j = 0; j < 64; ++j) {
      int nn = j * 64 + l;
      float4 v = xw[nn];
      float e = __fadd_rn(__fadd_rn(__fmul_rn(sx, v.x), __fmul_rn(sy, v.y)),
                          __fmul_rn(sz, v.z));
      float d = __fadd_rn(__fadd_rn(nxn, v.w), __fmul_rn(-2.0f, e));
      int sb = __float_as_int(d);
      u[j] = (sb < 0) ? ~((unsigned)sb) : (((unsigned)sb) | 0x80000000u);
    }
    // ---- top-K selection: grouped tournament + two-phase DPP reduce ----
    unsigned keep = 0;
#pragma unroll 1
    for (int p = 0; p < K_; ++p) {
      // per-lane argmin over u[0..63], lowest j wins ties (strict <, left-kept)
      unsigned gv[8], gj_[8];
#pragma unroll
      for (int g = 0; g < 8; ++g) {
        unsigned bv = u[g * 8];
        unsigned bj = (unsigned)(g * 8);
#pragma unroll
        for (int j2 = 1; j2 < 8; ++j2) {
          unsigned uu = u[g * 8 + j2];
          bool tk = uu < bv;
          bv = tk ? uu : bv;
          bj = tk ? (unsigned)(g * 8 + j2) : bj;
        }
        gv[g] = bv;
        gj_[g] = bj;
      }
#pragma unroll
      for (int st = 4; st >= 1; st >>= 1)
#pragma unroll
        for (int i2 = 0; i2 < 4; ++i2) {
          if (i2 < st) {
            bool tk = gv[i2 + st] < gv[i2];  // tie -> keep left (lower j)
            gv[i2] = tk ? gv[i2 + st] : gv[i2];
            gj_[i2] = tk ? gj_[i2 + st] : gj_[i2];
          }
        }
      // two-phase wave argmin: max of inverted value, then max of inverted
      // index among winners (inverted idx >= 0xFFFFF000 > 0, so a winner
      // always beats losers' 0). Exact same winner as the old u64 reduce.
      unsigned hi = ~gv[0];
      unsigned gidx = gj_[0] * 64u + (unsigned)l;
      unsigned vmax = wave_max_u32(hi);
      unsigned cand = (hi == vmax) ? ~gidx : 0u;
      unsigned cmax = wave_max_u32(cand);
      unsigned gn = ~cmax;  // global index of winner (min value, then min idx)
      if (l == p) keep = gn;
      if ((gn & 63u) == (unsigned)l) {
        int gj = (int)(gn >> 6);
#pragma unroll
        for (int j = 0; j < 64; ++j)
          if (j == gj) u[j] = 0xFFFFFFFFu;
      }
    }

    // ---- gemm0: two 16-row MFMA tiles for this sample ----
#pragma unroll 1
    for (int t2 = 0; t2 < 2; ++t2) {
      int rb = bs * 32 + t2 * 16;
      int idxr = __shfl((int)keep, t2 * 16 + n16);
      const float* pbase = points + (size_t)b * N_ * 64 + (size_t)idxr * 64;
      U4S8 af[3];
#pragma unroll
      for (int kc = 0; kc < 2; ++kc) {
        float4 va = *reinterpret_cast<const float4*>(pbase + kc * 32 + quad * 8);
        float4 vb = *reinterpret_cast<const float4*>(pbase + kc * 32 + quad * 8 + 4);
        af[kc].u = make_uint4(pkrne(va.x, va.y), pkrne(va.z, va.w),
                              pkrne(vb.x, vb.y), pkrne(vb.z, vb.w));
      }
      if (quad == 0) {
        float4 p4 = xw[idxr];
        float dx = __fsub_rn(p4.x, sx);
        float dy = __fsub_rn(p4.y, sy);
        float dz = __fsub_rn(p4.z, sz);
        af[2].u = make_uint4(pkrne(dx, dy), (unsigned)f2bf(dz), 0u, 0u);
      } else {
        af[2].u = make_uint4(0u, 0u, 0u, 0u);
      }
      floatx4 acc[4];
#pragma unroll
      for (int nt = 0; nt < 4; ++nt) acc[nt] = floatx4{0.f, 0.f, 0.f, 0.f};
#pragma unroll
      for (int kc = 0; kc < 3; ++kc)
#pragma unroll
        for (int nt = 0; nt < 4; ++nt)
          acc[nt] = __builtin_amdgcn_mfma_f32_16x16x32_bf16(
              af[kc].v, bf0[nt][kc].v, acc[nt], 0, 0, 0);
#pragma unroll
      for (int nt = 0; nt < 4; ++nt)
#pragma unroll
        for (int rI = 0; rI < 4; ++rI) {
          float ys = acc[nt][rI] + b0v[nt];
          ssum[nt] += ys;
          ssq[nt] = fmaf(ys, ys, ssq[nt]);
          ltw[(quad * 4 + rI) * 68 + nt * 16 + n16] = ys;
        }
      const float* lrow = ltw + n16 * 68 + quad * 16;
      float4 va = *reinterpret_cast<const float4*>(lrow);
      float4 vb = *reinterpret_cast<const float4*>(lrow + 4);
      float4 vc = *reinterpret_cast<const float4*>(lrow + 8);
      float4 vd = *reinterpret_cast<const float4*>(lrow + 12);
      ushort_t* yo = y0 + (size_t)(rb + n16) * 64 + quad * 16;
      *reinterpret_cast<uint4*>(yo) =
          make_uint4(pkhu(va.x, va.y), pkhu(va.z, va.w), pkhu(vb.x, vb.y), pkhu(vb.z, vb.w));
      *reinterpret_cast<uint4*>(yo + 8) =
          make_uint4(pkhu(vc.x, vc.y), pkhu(vc.z, vc.w), pkhu(vd.x, vd.y), pkhu(vd.z, vd.w));
    }
  }

  // ---- stats flush (once per wave) ----
  float* stp = stats + (size_t)(wid & (NSLOT - 1)) * 64 * 2;
#pragma unroll
  for (int nt = 0; nt < 4; ++nt) {
    float s = ssum[nt], q = ssq[nt];
    s += __shfl_down(s, 16); q += __shfl_down(q, 16);
    s += __shfl_down(s, 32); q += __shfl_down(q, 32);
    if (l < 16) {
      atomicAdd(&stp[(size_t)(nt * 16 + l) * 2 + 0], s);
      atomicAdd(&stp[(size_t)(nt * 16 + l) * 2 + 1], q);
    }
  }
}

// ================================================================ gemm1 (MFMA)
__global__ __launch_bounds__(256) void gemm1_mfma(
    const ushort_t* __restrict__ y0, const float* __restrict__ bnp,
    const ushort_t* __restrict__ wB1, const float* __restrict__ bias1,
    ushort_t* __restrict__ y1, float* __restrict__ stats) {
  __shared__ __align__(16) float lt[4][16 * 68];
  int t = threadIdx.x;
  int w = t >> 6, l = t & 63;
  int n = l & 15, quad = l >> 4;
  U4S8 bf[4][2];
#pragma unroll
  for (int nt = 0; nt < 4; ++nt)
#pragma unroll
    for (int kc = 0; kc < 2; ++kc)
      bf[nt][kc].u = *reinterpret_cast<const uint4*>(
          wB1 + (size_t)(nt * 16 + n) * 64 + kc * 32 + quad * 8);
  float4 scA[2], scB[2], shA[2], shB[2];
#pragma unroll
  for (int kc = 0; kc < 2; ++kc) {
    int cb = kc * 32 + quad * 8;
    scA[kc] = *reinterpret_cast<const float4*>(&bnp[cb]);
    scB[kc] = *reinterpret_cast<const float4*>(&bnp[cb + 4]);
    shA[kc] = *reinterpret_cast<const float4*>(&bnp[64 + cb]);
    shB[kc] = *reinterpret_cast<const float4*>(&bnp[64 + cb + 4]);
  }
  float b1v[4], ssum[4], ssq[4];
#pragma unroll
  for (int nt = 0; nt < 4; ++nt) {
    b1v[nt] = bias1[nt * 16 + n];
    ssum[nt] = 0.0f;
    ssq[nt] = 0.0f;
  }
  int rowbase0 = blockIdx.x * 1024 + w * 256;
  float* ltw = lt[w];
#pragma unroll 1
  for (int tile = 0; tile < 16; ++tile) {
    int rb = rowbase0 + tile * 16;
    U4S8 af[2];
#pragma unroll
    for (int kc = 0; kc < 2; ++kc) {
      uint4 xv = *reinterpret_cast<const uint4*>(
          y0 + (size_t)(rb + n) * 64 + kc * 32 + quad * 8);
      af[kc].u = bn_relu_pack(xv, scA[kc], scB[kc], shA[kc], shB[kc]);
    }
    floatx4 acc[4];
#pragma unroll
    for (int nt = 0; nt < 4; ++nt) acc[nt] = floatx4{0.f, 0.f, 0.f, 0.f};
#pragma unroll
    for (int kc = 0; kc < 2; ++kc)
#pragma unroll
      for (int nt = 0; nt < 4; ++nt)
        acc[nt] = __builtin_amdgcn_mfma_f32_16x16x32_bf16(
            af[kc].v, bf[nt][kc].v, acc[nt], 0, 0, 0);
#pragma unroll
    for (int nt = 0; nt < 4; ++nt)
#pragma unroll
      for (int rI = 0; rI < 4; ++rI) {
        float ys = acc[nt][rI] + b1v[nt];
        ssum[nt] += ys;
        ssq[nt] = fmaf(ys, ys, ssq[nt]);
        ltw[(quad * 4 + rI) * 68 + nt * 16 + n] = ys;
      }
    const float* lrow = ltw + n * 68 + quad * 16;
    float4 va = *reinterpret_cast<const float4*>(lrow);
    float4 vb = *reinterpret_cast<const float4*>(lrow + 4);
    float4 vc = *reinterpret_cast<const float4*>(lrow + 8);
    float4 vd = *reinterpret_cast<const float4*>(lrow + 12);
    ushort_t* yo = y1 + (size_t)(rb + n) * 64 + quad * 16;
    *reinterpret_cast<uint4*>(yo) =
        make_uint4(pkhu(va.x, va.y), pkhu(va.z, va.w), pkhu(vb.x, vb.y), pkhu(vb.z, vb.w));
    *reinterpret_cast<uint4*>(yo + 8) =
        make_uint4(pkhu(vc.x, vc.y), pkhu(vc.z, vc.w), pkhu(vd.x, vd.y), pkhu(vd.z, vd.w));
  }
  float* stp = stats + (size_t)((blockIdx.x * 4 + w) & (NSLOT - 1)) * 64 * 2;
#pragma unroll
  for (int nt = 0; nt < 4; ++nt) {
    float s = ssum[nt], q = ssq[nt];
    s += __shfl_down(s, 16); q += __shfl_down(q, 16);
    s += __shfl_down(s, 32); q += __shfl_down(q, 32);
    if (l < 16) {
      atomicAdd(&stp[(size_t)(nt * 16 + l) * 2 + 0], s);
      atomicAdd(&stp[(size_t)(nt * 16 + l) * 2 + 1], q);
    }
  }
}

// ================================================================ gemm2 (MFMA)
__global__ __launch_bounds__(256) void gemm2_mfma(
    const ushort_t* __restrict__ y1, const float* __restrict__ bnp,
    const ushort_t* __restrict__ wB2, const float* __restrict__ bias2,
    float* __restrict__ stats, float* __restrict__ maxY, float* __restrict__ minY) {
  int t = threadIdx.x;
  int w = t >> 6, l = t & 63;
  int n = l & 15, quad = l >> 4;
  U4S8 bf[8][2];
#pragma unroll
  for (int nt = 0; nt < 8; ++nt)
#pragma unroll
    for (int kc = 0; kc < 2; ++kc)
      bf[nt][kc].u = *reinterpret_cast<const uint4*>(
          wB2 + (size_t)(nt * 16 + n) * 64 + kc * 32 + quad * 8);
  float4 scA[2], scB[2], shA[2], shB[2];
#pragma unroll
  for (int kc = 0; kc < 2; ++kc) {
    int cb = kc * 32 + quad * 8;
    scA[kc] = *reinterpret_cast<const float4*>(&bnp[128 + cb]);
    scB[kc] = *reinterpret_cast<const float4*>(&bnp[128 + cb + 4]);
    shA[kc] = *reinterpret_cast<const float4*>(&bnp[192 + cb]);
    shB[kc] = *reinterpret_cast<const float4*>(&bnp[192 + cb + 4]);
  }
  float b2v[8], ssum[8], ssq[8], mxv[8], mnv[8];
#pragma unroll
  for (int nt = 0; nt < 8; ++nt) {
    b2v[nt] = bias2[nt * 16 + n];
    ssum[nt] = 0.0f;
    ssq[nt] = 0.0f;
    mxv[nt] = -3.4e38f;
    mnv[nt] = 3.4e38f;
  }
  int rowbase0 = blockIdx.x * 1024 + w * 256;
#pragma unroll 1
  for (int tile = 0; tile < 16; ++tile) {
    int rb = rowbase0 + tile * 16;
    U4S8 af[2];
#pragma unroll
    for (int kc = 0; kc < 2; ++kc) {
      uint4 xv = *reinterpret_cast<const uint4*>(
          y1 + (size_t)(rb + n) * 64 + kc * 32 + quad * 8);
      af[kc].u = bn_relu_pack(xv, scA[kc], scB[kc], shA[kc], shB[kc]);
    }
    floatx4 acc[8];
#pragma unroll
    for (int nt = 0; nt < 8; ++nt) acc[nt] = floatx4{0.f, 0.f, 0.f, 0.f};
#pragma unroll
    for (int kc = 0; kc < 2; ++kc)
#pragma unroll
      for (int nt = 0; nt < 8; ++nt)
        acc[nt] = __builtin_amdgcn_mfma_f32_16x16x32_bf16(
            af[kc].v, bf[nt][kc].v, acc[nt], 0, 0, 0);
#pragma unroll
    for (int nt = 0; nt < 8; ++nt)
#pragma unroll
      for (int rI = 0; rI < 4; ++rI) {
        float ya = acc[nt][rI] + b2v[nt];
        ssum[nt] += ya;
        ssq[nt] = fmaf(ya, ya, ssq[nt]);
        mxv[nt] = fmaxf(mxv[nt], ya);
        mnv[nt] = fminf(mnv[nt], ya);
      }
    if (tile & 1) {
      int sidx = (rowbase0 >> 5) + (tile >> 1);
#pragma unroll
      for (int nt = 0; nt < 8; ++nt) {
        float mx = mxv[nt], mn = mnv[nt];
        mx = fmaxf(mx, __shfl_down(mx, 16));
        mn = fminf(mn, __shfl_down(mn, 16));
        mx = fmaxf(mx, __shfl_down(mx, 32));
        mn = fminf(mn, __shfl_down(mn, 32));
        if (l < 16) {
          maxY[(size_t)sidx * 128 + nt * 16 + l] = mx;
          minY[(size_t)sidx * 128 + nt * 16 + l] = mn;
        }
        mxv[nt] = -3.4e38f;
        mnv[nt] = 3.4e38f;
      }
    }
  }
  float* stp = stats + (size_t)((blockIdx.x * 4 + w) & (NSLOT - 1)) * 128 * 2;
#pragma unroll
  for (int nt = 0; nt < 8; ++nt) {
    float s = ssum[nt], q = ssq[nt];
    s += __shfl_down(s, 16); q += __shfl_down(q, 16);
    s += __shfl_down(s, 32); q += __shfl_down(q, 32);
    if (l < 16) {
      atomicAdd(&stp[(size_t)(nt * 16 + l) * 2 + 0], s);
      atomicAdd(&stp[(size_t)(nt * 16 + l) * 2 + 1], q);
    }
  }
}

// ---------------------------------------------------------------- BN finalize
__global__ void bn_finalize(const float* __restrict__ st, int cout,
                            const float* __restrict__ gamma,
                            const float* __restrict__ beta,
                            float* __restrict__ scale, float* __restrict__ shift) {
  int o = threadIdx.x;
  if (o >= cout) return;
  float s = 0.0f, q = 0.0f;
  for (int i = 0; i < NSLOT; ++i) {
    s += st[((size_t)i * cout + o) * 2 + 0];
    q += st[((size_t)i * cout + o) * 2 + 1];
  }
  float mean = s * (1.0f / CNT_F);
  float var = q * (1.0f / CNT_F) - mean * mean;
  float sc = gamma[o] / sqrtf(var + 1e-5f);
  scale[o] = sc;
  shift[o] = beta[o] - mean * sc;
}

// ---------------------------------------------------------------- pooling
__global__ __launch_bounds__(256) void pool_kernel(
    const float* __restrict__ maxY, const float* __restrict__ minY,
    const float* __restrict__ bnp, float* __restrict__ out) {
  __shared__ float tile[128 * 65];
  int b = blockIdx.x >> 4;
  int sbase = (blockIdx.x & 15) * 64;
  int t = threadIdx.x;
#pragma unroll 4
  for (int i = 0; i < 32; ++i) {
    int e = i * 256 + t;
    int sl = e >> 7, o = e & 127;
    float sc = bnp[256 + o], sh = bnp[384 + o];
    size_t g = ((size_t)(b * S_ + sbase + sl)) * 128 + o;
    float v = (sc >= 0.0f) ? maxY[g] : minY[g];
    tile[o * 65 + sl] = fmaxf(fmaf(v, sc, sh), 0.0f);
  }
  __syncthreads();
  int sl = t & 63;
  for (int o2 = t >> 6; o2 < 128; o2 += 4) {
    out[((size_t)(b * 128 + o2)) * S_ + sbase + sl] = tile[o2 * 65 + sl];
  }
}

// ---------------------------------------------------------------- launch
static inline size_t alup(size_t x) { return (x + 255) & ~(size_t)255; }

extern "C" void kernel_launch(void* const* d_in, const int* in_sizes, int n_in,
                              void* d_out, int out_size, void* d_ws, size_t ws_size,
                              hipStream_t stream) {
  (void)in_sizes; (void)n_in; (void)out_size;
  const float* xyz = (const float*)d_in[0];
  const float* points = (const float*)d_in[1];
  const float* w0 = (const float*)d_in[2];
  const float* b0 = (const float*)d_in[3];
  const float* g0 = (const float*)d_in[4];
  const float* be0 = (const float*)d_in[5];
  const float* w1 = (const float*)d_in[6];
  const float* b1 = (const float*)d_in[7];
  const float* g1 = (const float*)d_in[8];
  const float* be1 = (const float*)d_in[9];
  const float* w2 = (const float*)d_in[10];
  const float* b2 = (const float*)d_in[11];
  const float* g2 = (const float*)d_in[12];
  const float* be2 = (const float*)d_in[13];
  float* out_newxyz = (float*)d_out;
  float* out_newpts = out_newxyz + (size_t)B_ * S_ * 3;

  char* p = (char*)d_ws;
  int* pub = (int*)p;      p += alup((size_t)B_ * S_ * 4);
  float4* xyzw = (float4*)p; p += alup((size_t)B_ * N_ * 16);
  float* st0 = (float*)p;  p += (size_t)NSLOT * 64 * 2 * 4;
  float* st1 = (float*)p;  p += (size_t)NSLOT * 64 * 2 * 4;
  float* st2 = (float*)p;  p += (size_t)NSLOT * 128 * 2 * 4;
  float* bnp = (float*)p;  p += alup(512 * 4);
  ushort_t* wB0 = (ushort_t*)p; p += alup(64 * 96 * 2);
  ushort_t* wB1 = (ushort_t*)p; p += alup(64 * 64 * 2);
  ushort_t* wB2 = (ushort_t*)p; p += alup(128 * 64 * 2);
  float* maxY = (float*)p; p += (size_t)B_ * S_ * 128 * 4;
  float* minY = (float*)p; p += (size_t)B_ * S_ * 128 * 4;
  ushort_t* y0 = (ushort_t*)p; p += (size_t)RWS * 64 * 2;
  ushort_t* y1 = (ushort_t*)p; p += (size_t)RWS * 64 * 2;
  if ((size_t)(p - (char*)d_ws) > ws_size) return;  // visible failure

  float* sc0 = bnp;       float* sh0 = bnp + 64;
  float* sc1 = bnp + 128; float* sh1 = bnp + 192;
  float* sc2 = bnp + 256; float* sh2 = bnp + 384;

  hipMemsetAsync(st0, 0, (size_t)NSLOT * (64 + 64 + 128) * 2 * 4, stream);
  hipMemsetAsync(pub, 0, (size_t)B_ * S_ * 4, stream);
  prep_all<<<256, 256, 0, stream>>>(xyz, xyzw, w0, w1, w2, wB0, wB1, wB2);
  fused_kernel<<<NBLK, 256, 0, stream>>>(
      xyz, points, xyzw, wB0, b0, pub, out_newxyz, y0, st0);
  bn_finalize<<<1, 128, 0, stream>>>(st0, 64, g0, be0, sc0, sh0);
  gemm1_mfma<<<RWS / 1024, 256, 0, stream>>>(y0, bnp, wB1, b1, y1, st1);
  bn_finalize<<<1, 128, 0, stream>>>(st1, 64, g1, be1, sc1, sh1);
  gemm2_mfma<<<RWS / 1024, 256, 0, stream>>>(y1, bnp, wB2, b2, st2, maxY, minY);
  bn_finalize<<<1, 128, 0, stream>>>(st2, 128, g2, be2, sc2, sh2);
  pool_kernel<<<B_ * (S_ / 64), 256, 0, stream>>>(maxY, minY, bnp, out_newpts);
}